// Round 6
// baseline (209.843 us; speedup 1.0000x reference)
//
#include <hip/hip_runtime.h>
#include <hip/hip_bf16.h>

// LocalAttn: B=8 S=1024 E=512 H=16 D=32, rel-pos bias, NO causal mask.
// f32 inputs / f32 output. Internals bf16 for MFMA.
// R12: attn = R11 block-level K/V staging x R10 occupancy. Grid 2048,
// ONE 16-row strip/wave, block = 64 rows; K/V staged once per block-iter
// (VMEM cost per BLOCK, not per wave -> more waves are ~free); Er rotated
// per wave (e0'=e4, 4 new loads/iter). Per CU-iter VMEM 192 (< R7's 224),
// K/V bytes 64KB (< R7's 128KB). LDS 18.4KB -> 8 blocks/CU; single-strip
// regs ~64-76 VGPR -> 7-8 waves/SIMD vs 4. Eliminated theories: VALU
// (R7 -2.8%), per-wave ILP (R8 spill), waves w/o sharing (R10 worse),
// VMEM reqs (R11 -4.6%). Remaining: latency-bound at 4 waves/SIMD.
// proj/convert unchanged.

typedef short bf16x8 __attribute__((ext_vector_type(8)));   // 8 bf16 (4 VGPRs)
typedef float f32x4 __attribute__((ext_vector_type(4)));
typedef unsigned int u32x2 __attribute__((ext_vector_type(2)));
typedef unsigned int u32x4 __attribute__((ext_vector_type(4)));

#if __has_builtin(__builtin_amdgcn_exp2f)
#define EXP2F(x) __builtin_amdgcn_exp2f(x)
#else
#define EXP2F(x) exp2f(x)
#endif

constexpr int Bb = 8, Ss = 1024, Ee = 512, Hh = 16, Dd = 32;
// log2(e)/sqrt(32): folds the 1/sqrt(D) softmax scale and exp->exp2 into Q.
#define QSCALE 0.25503486f

__device__ __forceinline__ bf16x8 ldg_frag(const __hip_bfloat16* p) {
    return *reinterpret_cast<const bf16x8*>(p);
}

// hardware packed f32->bf16 (RNE), lo in [15:0], hi in [31:16].
__device__ __forceinline__ unsigned pack_bf16(float lo, float hi) {
    unsigned r;
    asm("v_cvt_pk_bf16_f32 %0, %1, %2" : "=v"(r) : "v"(lo), "v"(hi));
    return r;
}

__device__ __forceinline__ float bperm_f(int addr, float v) {
    return __builtin_bit_cast(float,
        __builtin_amdgcn_ds_bpermute(addr, __builtin_bit_cast(int, v)));
}

// async global->LDS, 16B/lane; LDS dest = uniform base + lane*16.
__device__ __forceinline__ void stage16(const void* g, void* l) {
    typedef const __attribute__((address_space(1))) char gch;
    typedef __attribute__((address_space(3))) char lch;
    __builtin_amdgcn_global_load_lds((gch*)g, (lch*)l, 16, 0, 0);
}

// ---------------- f32 -> bf16 conversion into workspace -------------------
__global__ __launch_bounds__(256) void convert_kernel(
    const float* __restrict__ x,  const float* __restrict__ wq,
    const float* __restrict__ wk, const float* __restrict__ wv,
    const float* __restrict__ er,
    __hip_bfloat16* __restrict__ xb, __hip_bfloat16* __restrict__ wb,
    __hip_bfloat16* __restrict__ erb)
{
    const int GX = 1048576, GW = 65536, GE = 16376;  // in float4 groups
    int g = blockIdx.x * 256 + threadIdx.x;
    if (g >= GX + 3 * GW + GE) return;
    const float* src;
    __hip_bfloat16* dst;
    int rel;
    if (g < GX)               { src = x;  dst = xb;          rel = g; }
    else if (g < GX +   GW)   { src = wq; dst = wb;          rel = g - GX; }
    else if (g < GX + 2*GW)   { src = wk; dst = wb + 262144; rel = g - GX - GW; }
    else if (g < GX + 3*GW)   { src = wv; dst = wb + 524288; rel = g - GX - 2*GW; }
    else                      { src = er; dst = erb;         rel = g - GX - 3*GW; }
    const float4 v = *reinterpret_cast<const float4*>(src + (size_t)rel * 4);
    u32x2 pk;
    pk[0] = pack_bf16(v.x, v.y);
    pk[1] = pack_bf16(v.z, v.w);
    *reinterpret_cast<u32x2*>(dst + (size_t)rel * 4) = pk;
}

// ---------------- projection: Q/K/V = x @ W^T ------------------------------
// grid (6,128): WG = 64 rows x 256 cols of [Q|K|V]; wave = 64x64.
// V epilogue writes INTERLEAVED Vti: u32[d][512], slot (s>>5)*16+(s&15)
// packs the bf16 pair (V[s], V[s+16]) of each 32-block.
__global__ __launch_bounds__(256) void proj_kernel(
    const __hip_bfloat16* __restrict__ xb,   // [8192][512]
    const __hip_bfloat16* __restrict__ wb,   // [1536][512]
    __hip_bfloat16* __restrict__ Qs,   // [B][H][S][D], scaled by QSCALE
    __hip_bfloat16* __restrict__ Kh,   // [B][H][S][D]
    unsigned* __restrict__ Vt32)       // [B][H][D][512 u32] interleaved
{
    const int tid  = threadIdx.x;
    const int wave = tid >> 6;
    const int lane = tid & 63;
    const int li   = lane & 15;
    const int quad = lane >> 4;

    const int m0    = blockIdx.y * 64;
    const int nbase = blockIdx.x * 256 + wave * 64;   // multiple of 64

    f32x4 acc[4][4];
    #pragma unroll
    for (int rf = 0; rf < 4; ++rf)
        #pragma unroll
        for (int t = 0; t < 4; ++t) acc[rf][t] = f32x4{0.f, 0.f, 0.f, 0.f};

    const __hip_bfloat16* xp = xb + (size_t)(m0 + li) * Ee + quad * 8;
    const __hip_bfloat16* wp = wb + (size_t)(nbase + li) * Ee + quad * 8;

    for (int k0 = 0; k0 < Ee; k0 += 32) {
        bf16x8 a[4], bfr[4];
        #pragma unroll
        for (int rf = 0; rf < 4; ++rf) a[rf]  = ldg_frag(xp + rf * 16 * Ee + k0);
        #pragma unroll
        for (int t = 0; t < 4; ++t)    bfr[t] = ldg_frag(wp + t * 16 * Ee + k0);
        #pragma unroll
        for (int rf = 0; rf < 4; ++rf)
            #pragma unroll
            for (int t = 0; t < 4; ++t)
                acc[rf][t] = __builtin_amdgcn_mfma_f32_16x16x32_bf16(
                    a[rf], bfr[t], acc[rf][t], 0, 0, 0);
    }

    // epilogue. C layout: col = li, row = quad*4 + reg.
    const int mat = nbase >> 9;        // 0=Q 1=K 2=V (uniform per wave)
    const int nn0 = nbase & 511;
    const int bb  = m0 >> 10;          // 64-row block never straddles b
    const int sb  = m0 & 1023;
    if (mat == 2) {
        #pragma unroll
        for (int t = 0; t < 4; ++t) {
            int nn = nn0 + t * 16 + li;
            int h = nn >> 5, d = nn & 31;
            size_t base = ((size_t)(bb * Hh + h) * Dd + d) * 512
                        + (sb >> 5) * 16 + quad * 4;
            #pragma unroll
            for (int p = 0; p < 2; ++p) {      // rf pair (2p, 2p+1)
                u32x4 pk;
                #pragma unroll
                for (int r = 0; r < 4; ++r)
                    pk[r] = pack_bf16(acc[2*p][t][r], acc[2*p+1][t][r]);
                *reinterpret_cast<u32x4*>(Vt32 + base + (size_t)p * 16) = pk;
            }
        }
    } else {
        __hip_bfloat16* dst = (mat == 0) ? Qs : Kh;
        const float sc = (mat == 0) ? QSCALE : 1.0f;
        #pragma unroll
        for (int rf = 0; rf < 4; ++rf) {
            const int srow = sb + rf * 16 + quad * 4;
            #pragma unroll
            for (int t = 0; t < 4; ++t) {
                int nn = nn0 + t * 16 + li;
                int h = nn >> 5, d = nn & 31;
                size_t base = ((size_t)(bb * Hh + h) * Ss + srow) * Dd + d;
                #pragma unroll
                for (int r = 0; r < 4; r += 2) {
                    unsigned w = pack_bf16(acc[rf][t][r]     * sc,
                                           acc[rf][t][r + 1] * sc);
                    dst[base + (size_t)r * Dd] =
                        __builtin_bit_cast(__hip_bfloat16, (unsigned short)(w & 0xffffu));
                    dst[base + (size_t)(r + 1) * Dd] =
                        __builtin_bit_cast(__hip_bfloat16, (unsigned short)(w >> 16));
                }
            }
        }
    }
}

// ---------------- attention -----------------------------------------------
// grid 2048; (b,h) = blockIdx&127 (XCD-local: stride-128 blocks share
// (b,h) and the same XCD), ib = blockIdx>>7 in [0,16).
// Block covers 64 q-rows; wave owns ONE 16-row strip (i0 = ib*64+wave*16).
// Per block-iter: K/V tiles staged once into LDS (R11 code verbatim);
// per wave-iter VMEM = 2 staging + 4 Er (rotated window).
__global__ __launch_bounds__(256) void attn_kernel(
    const __hip_bfloat16* __restrict__ Qs,
    const __hip_bfloat16* __restrict__ Kh,
    const __hip_bfloat16* __restrict__ Vt,   // bf16 view of Vti (same bytes)
    const __hip_bfloat16* __restrict__ Er,   // [2048][32] bf16 (row 2047 pad)
    float* __restrict__ out)                 // [B][S][E] f32
{
    const int tid  = threadIdx.x;
    const int wave = tid >> 6;
    const int lane = tid & 63;
    const int li   = lane & 15;
    const int quad = lane >> 4;

    const int c  = blockIdx.x & 127;
    const int b  = c >> 4;
    const int h  = c & 15;
    const int ib = blockIdx.x >> 7;          // 0..15
    const int i0 = ib * 64 + wave * 16;      // this wave's 16 rows

    const __hip_bfloat16* Qp  = Qs + (size_t)(b * Hh + h) * Ss * Dd;
    const __hip_bfloat16* Kp  = Kh + (size_t)(b * Hh + h) * Ss * Dd;
    const unsigned*       Vp32 = reinterpret_cast<const unsigned*>(Vt)
                               + (size_t)(b * Hh + h) * Dd * 512;

    __shared__ unsigned pb_lds[4][2][16 * 20];       // 10240 B
    __shared__ __align__(16) unsigned char kvbuf[8192];  // K 4KB @0, V 4KB @4096
    unsigned* pb0 = pb_lds[wave][0];   // cols 0-31
    unsigned* pb1 = pb_lds[wave][1];   // cols 32-63

    const bf16x8 qf = ldg_frag(Qp + (i0 + li) * Dd + quad * 8);

    // loop-invariant: bpermute byte-addresses and SOURCE-side band-half
    // selector (see R7 comments). 1 bpermute per band value.
    int addr4[4];
    bool sel[4];
    #pragma unroll
    for (int r = 0; r < 4; ++r) {
        const int row = quad * 4 + r;
        addr4[r] = (16 * quad + ((li - row + 15) & 15)) * 4;
        sel[r]   = (li + row >= 15);       // this lane is a lower-block src
    }
    const int pbw = quad * 80 + li;        // pb write base (u32)
    const int pbr = li * 20 + quad * 4;    // pb read base (16B aligned)

    // staging addresses (R11 verbatim).
    // K quarter: lane l -> local row wave*16 + (l>>2), col-byte (l&3)*16.
    const int krow = wave * 16 + (lane >> 2);
    const int kcol8 = (lane & 3) * 8;                    // bf16 elems
    char* kdst = (char*)kvbuf + wave * 1024;
    // V quarter: lane l -> local row wave*8 + (l>>3); source col-byte is
    // XOR-swizzled so the LINEAR LDS write realizes lds[row][cb^sw]=V[row][cb].
    const int vrow = wave * 8 + (lane >> 3);
    const int vcol4 = 4 * ((lane & 7) ^ ((lane >> 3) & 7));  // u32 within row
    char* vdst = (char*)kvbuf + 4096 + wave * 1024;
    const int swz = (li & 7) << 4;       // read-side XOR (row li & li+16 alike)

    f32x4 o0 = f32x4{0,0,0,0}, o1 = f32x4{0,0,0,0};
    f32x4 ls = f32x4{0,0,0,0};
    const f32x4 zero = f32x4{0,0,0,0};

    bf16x8 ones;
    #pragma unroll
    for (int i = 0; i < 8; ++i) ones[i] = (short)0x3F80;   // bf16 1.0

    // Er rotation peel: window slides by 64 each iter; e0' = e4.
    const int rb0 = 1008 - i0;               // >= 0 for all i0
    bf16x8 e0 = ldg_frag(Er + (rb0 + li) * Dd + quad * 8);

    for (int j0 = 0; j0 < Ss; j0 += 64) {
        // ---- stage K (64x32) + V (32x64, interleaved) tiles into LDS ----
        stage16(Kp + (size_t)(j0 + krow) * Dd + kcol8, kdst);
        stage16(Vp32 + (size_t)vrow * 512 + (j0 >> 1) + vcol4, vdst);

        // ---- Er loads (new window rows; overlap staging latency) ----
        const int rb = j0 - i0 + 1008;
        bf16x8 e1 = ldg_frag(Er + (rb + 16 + li) * Dd + quad * 8);
        bf16x8 e2 = ldg_frag(Er + (rb + 32 + li) * Dd + quad * 8);
        bf16x8 e3 = ldg_frag(Er + (rb + 48 + li) * Dd + quad * 8);
        bf16x8 e4 = ldg_frag(Er + (rb + 64 + li) * Dd + quad * 8);

        // implicit s_waitcnt vmcnt(0) lgkmcnt(0) + s_barrier: every wave's
        // staging loads have landed before anyone reads the tiles.
        __syncthreads();

        // ---- K/V fragments from LDS ----
        const char* Kb = (const char*)kvbuf;
        const char* Vb = (const char*)kvbuf + 4096;
        bf16x8 k0 = *reinterpret_cast<const bf16x8*>(Kb + (     li) * 64 + quad * 16);
        bf16x8 k1 = *reinterpret_cast<const bf16x8*>(Kb + (16 + li) * 64 + quad * 16);
        bf16x8 k2 = *reinterpret_cast<const bf16x8*>(Kb + (32 + li) * 64 + quad * 16);
        bf16x8 k3 = *reinterpret_cast<const bf16x8*>(Kb + (48 + li) * 64 + quad * 16);
        bf16x8 v0 = *reinterpret_cast<const bf16x8*>(Vb + (     li) * 128 + ((     quad * 16) ^ swz));
        bf16x8 v1 = *reinterpret_cast<const bf16x8*>(Vb + (16 + li) * 128 + ((     quad * 16) ^ swz));
        bf16x8 v2 = *reinterpret_cast<const bf16x8*>(Vb + (     li) * 128 + ((64 + quad * 16) ^ swz));
        bf16x8 v3 = *reinterpret_cast<const bf16x8*>(Vb + (16 + li) * 128 + ((64 + quad * 16) ^ swz));

        // ---- QK + band MFMAs ----
        __builtin_amdgcn_s_setprio(1);
        f32x4 s0 = __builtin_amdgcn_mfma_f32_16x16x32_bf16(qf, k0, zero, 0, 0, 0);
        f32x4 s1 = __builtin_amdgcn_mfma_f32_16x16x32_bf16(qf, k1, zero, 0, 0, 0);
        f32x4 s2 = __builtin_amdgcn_mfma_f32_16x16x32_bf16(qf, k2, zero, 0, 0, 0);
        f32x4 s3 = __builtin_amdgcn_mfma_f32_16x16x32_bf16(qf, k3, zero, 0, 0, 0);
        f32x4 q0 = __builtin_amdgcn_mfma_f32_16x16x32_bf16(qf, e0, zero, 0, 0, 0);
        f32x4 q1 = __builtin_amdgcn_mfma_f32_16x16x32_bf16(qf, e1, zero, 0, 0, 0);
        f32x4 q2 = __builtin_amdgcn_mfma_f32_16x16x32_bf16(qf, e2, zero, 0, 0, 0);
        f32x4 q3 = __builtin_amdgcn_mfma_f32_16x16x32_bf16(qf, e3, zero, 0, 0, 0);
        f32x4 q4 = __builtin_amdgcn_mfma_f32_16x16x32_bf16(qf, e4, zero, 0, 0, 0);
        __builtin_amdgcn_s_setprio(0);

        // ---- softmax numerator -> pb ----
        float p0[4], p1[4], p2[4], p3[4];
        #pragma unroll
        for (int r = 0; r < 4; ++r) {
            float m0 = sel[r] ? q0[r] : q1[r];
            float m1 = sel[r] ? q1[r] : q2[r];
            float m2 = sel[r] ? q2[r] : q3[r];
            float m3 = sel[r] ? q3[r] : q4[r];
            p0[r] = EXP2F(s0[r] + bperm_f(addr4[r], m0));
            p1[r] = EXP2F(s1[r] + bperm_f(addr4[r], m1));
            p2[r] = EXP2F(s2[r] + bperm_f(addr4[r], m2));
            p3[r] = EXP2F(s3[r] + bperm_f(addr4[r], m3));
        }
        #pragma unroll
        for (int r = 0; r < 4; ++r) {
            pb0[pbw + 20 * r] = pack_bf16(p0[r], p1[r]);
            pb1[pbw + 20 * r] = pack_bf16(p2[r], p3[r]);
        }

        // ---- PV + ones-rowsum ----
        bf16x8 pf0 = *reinterpret_cast<const bf16x8*>(&pb0[pbr]);
        bf16x8 pf1 = *reinterpret_cast<const bf16x8*>(&pb1[pbr]);
        __builtin_amdgcn_s_setprio(1);
        o0 = __builtin_amdgcn_mfma_f32_16x16x32_bf16(pf0, v0, o0, 0, 0, 0);
        o1 = __builtin_amdgcn_mfma_f32_16x16x32_bf16(pf0, v1, o1, 0, 0, 0);
        o0 = __builtin_amdgcn_mfma_f32_16x16x32_bf16(pf1, v2, o0, 0, 0, 0);
        o1 = __builtin_amdgcn_mfma_f32_16x16x32_bf16(pf1, v3, o1, 0, 0, 0);
        ls = __builtin_amdgcn_mfma_f32_16x16x32_bf16(pf0, ones, ls, 0, 0, 0);
        ls = __builtin_amdgcn_mfma_f32_16x16x32_bf16(pf1, ones, ls, 0, 0, 0);
        __builtin_amdgcn_s_setprio(0);

        // rotate Er window; keep kv buffer safe for next iter's staging.
        e0 = e4;
        __syncthreads();
    }

    // ones-MFMA accumulated exact row sums in the same C layout as o0/o1.
    #pragma unroll
    for (int r = 0; r < 4; ++r) ls[r] = 1.0f / ls[r];
    #pragma unroll
    for (int r = 0; r < 4; ++r) {
        const int srow = i0 + quad * 4 + r;
        float* op = out + ((size_t)b * Ss + srow) * Ee + h * Dd;
        op[li]      = o0[r] * ls[r];
        op[16 + li] = o1[r] * ls[r];
    }
}

extern "C" void kernel_launch(void* const* d_in, const int* in_sizes, int n_in,
                              void* d_out, int out_size, void* d_ws, size_t ws_size,
                              hipStream_t stream) {
    const float* x  = (const float*)d_in[0];
    const float* Wq = (const float*)d_in[1];
    const float* Wk = (const float*)d_in[2];
    const float* Wv = (const float*)d_in[3];
    const float* Er = (const float*)d_in[4];
    float* out = (float*)d_out;

    // ws layout (bf16 elements; all offsets 16B-aligned)
    __hip_bfloat16* xb  = reinterpret_cast<__hip_bfloat16*>(d_ws);
    __hip_bfloat16* wbb = xb  + (size_t)8192 * 512;
    __hip_bfloat16* erb = wbb + (size_t)1536 * 512;
    __hip_bfloat16* Qs  = erb + 65536;                  // row 2047 = pad
    __hip_bfloat16* Kh  = Qs  + (size_t)Bb * Hh * Ss * Dd;
    __hip_bfloat16* Vt  = Kh  + (size_t)Bb * Hh * Ss * Dd;

    convert_kernel<<<4929, 256, 0, stream>>>(x, Wq, Wk, Wv, Er, xb, wbb, erb);
    proj_kernel<<<dim3(6, 128), 256, 0, stream>>>(
        xb, wbb, Qs, Kh, reinterpret_cast<unsigned*>(Vt));
    attn_kernel<<<dim3(2048), 256, 0, stream>>>(Qs, Kh, Vt, erb, out);
}

// Round 7
// 166.804 us; speedup vs baseline: 1.2580x; 1.2580x over previous
//
#include <hip/hip_runtime.h>
#include <hip/hip_bf16.h>

// LocalAttn: B=8 S=1024 E=512 H=16 D=32, rel-pos bias, NO causal mask.
// f32 inputs / f32 output. Internals bf16 for MFMA.
// R13: (a) attn = R11 verbatim (78.5us best) + K-tile bank-conflict fix:
// K staged with pre-swizzled source chunk ((l&3)^((l>>3)&3)) and read
// chunk quad^((li>>1)&3) -> 8-way conflict becomes free 2-way (V already
// had this; K was my oversight). (b) proj -> m97 staged-GEMM recipe at
// same 64x256 geometry: per K-step stage A(64x32)+B(256x32) via 5
// global_load_lds/wave (A staged ONCE per block, was 4x redundant),
// swizzled ds_read_b128 (2-way free), 16 MFMAs, 2 barriers. Same values,
// same accumulation order, epilogues untouched. Readout: total-minus-attn
// isolates proj's true share of the ~125us unmeasured residual.

typedef short bf16x8 __attribute__((ext_vector_type(8)));   // 8 bf16 (4 VGPRs)
typedef float f32x4 __attribute__((ext_vector_type(4)));
typedef unsigned int u32x2 __attribute__((ext_vector_type(2)));
typedef unsigned int u32x4 __attribute__((ext_vector_type(4)));

#if __has_builtin(__builtin_amdgcn_exp2f)
#define EXP2F(x) __builtin_amdgcn_exp2f(x)
#else
#define EXP2F(x) exp2f(x)
#endif

constexpr int Bb = 8, Ss = 1024, Ee = 512, Hh = 16, Dd = 32;
// log2(e)/sqrt(32): folds the 1/sqrt(D) softmax scale and exp->exp2 into Q.
#define QSCALE 0.25503486f

__device__ __forceinline__ bf16x8 ldg_frag(const __hip_bfloat16* p) {
    return *reinterpret_cast<const bf16x8*>(p);
}

// hardware packed f32->bf16 (RNE), lo in [15:0], hi in [31:16].
__device__ __forceinline__ unsigned pack_bf16(float lo, float hi) {
    unsigned r;
    asm("v_cvt_pk_bf16_f32 %0, %1, %2" : "=v"(r) : "v"(lo), "v"(hi));
    return r;
}

__device__ __forceinline__ float bperm_f(int addr, float v) {
    return __builtin_bit_cast(float,
        __builtin_amdgcn_ds_bpermute(addr, __builtin_bit_cast(int, v)));
}

// async global->LDS, 16B/lane; LDS dest = wave-uniform base + lane*16.
__device__ __forceinline__ void stage16(const void* g, void* l) {
    typedef const __attribute__((address_space(1))) char gch;
    typedef __attribute__((address_space(3))) char lch;
    __builtin_amdgcn_global_load_lds((gch*)g, (lch*)l, 16, 0, 0);
}

// ---------------- f32 -> bf16 conversion into workspace -------------------
__global__ __launch_bounds__(256) void convert_kernel(
    const float* __restrict__ x,  const float* __restrict__ wq,
    const float* __restrict__ wk, const float* __restrict__ wv,
    const float* __restrict__ er,
    __hip_bfloat16* __restrict__ xb, __hip_bfloat16* __restrict__ wb,
    __hip_bfloat16* __restrict__ erb)
{
    const int GX = 1048576, GW = 65536, GE = 16376;  // in float4 groups
    int g = blockIdx.x * 256 + threadIdx.x;
    if (g >= GX + 3 * GW + GE) return;
    const float* src;
    __hip_bfloat16* dst;
    int rel;
    if (g < GX)               { src = x;  dst = xb;          rel = g; }
    else if (g < GX +   GW)   { src = wq; dst = wb;          rel = g - GX; }
    else if (g < GX + 2*GW)   { src = wk; dst = wb + 262144; rel = g - GX - GW; }
    else if (g < GX + 3*GW)   { src = wv; dst = wb + 524288; rel = g - GX - 2*GW; }
    else                      { src = er; dst = erb;         rel = g - GX - 3*GW; }
    const float4 v = *reinterpret_cast<const float4*>(src + (size_t)rel * 4);
    u32x2 pk;
    pk[0] = pack_bf16(v.x, v.y);
    pk[1] = pack_bf16(v.z, v.w);
    *reinterpret_cast<u32x2*>(dst + (size_t)rel * 4) = pk;
}

// ---------------- projection: Q/K/V = x @ W^T ------------------------------
// grid (6,128): WG = 64 rows x 256 cols of [Q|K|V]; wave = 64x64.
// m97-style: per K-step (BK=32) the block stages A-tile 64x32 (4KB, once)
// and B-tile 256x32 (16KB) via global_load_lds; swizzled ds_read_b128.
// Swizzle: lds[row][c] = src[row][c ^ ((row>>1)&3)] (chunk = 16B); source
// pre-swizzled (linear LDS dest), read XORs the same term -> identity.
// V epilogue writes INTERLEAVED Vti: u32[d][512], slot (s>>5)*16+(s&15)
// packs the bf16 pair (V[s], V[s+16]) of each 32-block.
__global__ __launch_bounds__(256) void proj_kernel(
    const __hip_bfloat16* __restrict__ xb,   // [8192][512]
    const __hip_bfloat16* __restrict__ wb,   // [1536][512]
    __hip_bfloat16* __restrict__ Qs,   // [B][H][S][D], scaled by QSCALE
    __hip_bfloat16* __restrict__ Kh,   // [B][H][S][D]
    unsigned* __restrict__ Vt32)       // [B][H][D][512 u32] interleaved
{
    const int tid  = threadIdx.x;
    const int wave = tid >> 6;
    const int lane = tid & 63;
    const int li   = lane & 15;
    const int quad = lane >> 4;

    const int m0    = blockIdx.y * 64;
    const int nbase = blockIdx.x * 256 + wave * 64;   // multiple of 64

    __shared__ __align__(16) char smem[20480];   // A 4KB @0, B 16KB @4096

    f32x4 acc[4][4];
    #pragma unroll
    for (int rf = 0; rf < 4; ++rf)
        #pragma unroll
        for (int t = 0; t < 4; ++t) acc[rf][t] = f32x4{0.f, 0.f, 0.f, 0.f};

    // staging: lane l covers row (l>>2) of its 16-row group, 16B chunk
    // (l&3) of the 64B k-slice; source chunk pre-XOR'd by s(row)=(l>>3)&3.
    const int srow   = lane >> 2;
    const int schunk = ((lane & 3) ^ ((lane >> 3) & 3)) << 4;   // bytes
    const char* Asrc = (const char*)xb
        + (((size_t)(m0 + wave * 16 + srow)) << 10) + schunk;   // row*1024B
    const char* Bsrc = (const char*)wb
        + (((size_t)(blockIdx.x * 256 + wave * 64 + srow)) << 10) + schunk;
    char* Adst = smem + wave * 1024;
    char* Bdst = smem + 4096 + wave * 4096;

    // read-side chunk: quad ^ s(row); s(row)=(li>>1)&3 for all frag rows.
    const int rchunk = (quad ^ ((li >> 1) & 3)) << 4;

    for (int k0 = 0; k0 < Ee; k0 += 32) {
        const int kb = k0 * 2;                 // byte offset within row
        stage16(Asrc + kb,         Adst);
        stage16(Bsrc + kb,         Bdst);
        stage16(Bsrc + kb + 16384, Bdst + 1024);   // +16 rows
        stage16(Bsrc + kb + 32768, Bdst + 2048);   // +32 rows
        stage16(Bsrc + kb + 49152, Bdst + 3072);   // +48 rows
        __syncthreads();   // implicit vmcnt(0): staging landed block-wide

        bf16x8 a[4], bfr[4];
        #pragma unroll
        for (int rf = 0; rf < 4; ++rf)
            a[rf] = *reinterpret_cast<const bf16x8*>(
                smem + (rf * 16 + li) * 64 + rchunk);
        #pragma unroll
        for (int t = 0; t < 4; ++t)
            bfr[t] = *reinterpret_cast<const bf16x8*>(
                smem + 4096 + (wave * 64 + t * 16 + li) * 64 + rchunk);
        #pragma unroll
        for (int rf = 0; rf < 4; ++rf)
            #pragma unroll
            for (int t = 0; t < 4; ++t)
                acc[rf][t] = __builtin_amdgcn_mfma_f32_16x16x32_bf16(
                    a[rf], bfr[t], acc[rf][t], 0, 0, 0);
        __syncthreads();   // protect tiles from next step's staging
    }

    // epilogue. C layout: col = li, row = quad*4 + reg.
    const int mat = nbase >> 9;        // 0=Q 1=K 2=V (uniform per wave)
    const int nn0 = nbase & 511;
    const int bb  = m0 >> 10;          // 64-row block never straddles b
    const int sb  = m0 & 1023;
    if (mat == 2) {
        #pragma unroll
        for (int t = 0; t < 4; ++t) {
            int nn = nn0 + t * 16 + li;
            int h = nn >> 5, d = nn & 31;
            size_t base = ((size_t)(bb * Hh + h) * Dd + d) * 512
                        + (sb >> 5) * 16 + quad * 4;
            #pragma unroll
            for (int p = 0; p < 2; ++p) {      // rf pair (2p, 2p+1)
                u32x4 pk;
                #pragma unroll
                for (int r = 0; r < 4; ++r)
                    pk[r] = pack_bf16(acc[2*p][t][r], acc[2*p+1][t][r]);
                *reinterpret_cast<u32x4*>(Vt32 + base + (size_t)p * 16) = pk;
            }
        }
    } else {
        __hip_bfloat16* dst = (mat == 0) ? Qs : Kh;
        const float sc = (mat == 0) ? QSCALE : 1.0f;
        #pragma unroll
        for (int rf = 0; rf < 4; ++rf) {
            const int srw = sb + rf * 16 + quad * 4;
            #pragma unroll
            for (int t = 0; t < 4; ++t) {
                int nn = nn0 + t * 16 + li;
                int h = nn >> 5, d = nn & 31;
                size_t base = ((size_t)(bb * Hh + h) * Ss + srw) * Dd + d;
                #pragma unroll
                for (int r = 0; r < 4; r += 2) {
                    unsigned w = pack_bf16(acc[rf][t][r]     * sc,
                                           acc[rf][t][r + 1] * sc);
                    dst[base + (size_t)r * Dd] =
                        __builtin_bit_cast(__hip_bfloat16, (unsigned short)(w & 0xffffu));
                    dst[base + (size_t)(r + 1) * Dd] =
                        __builtin_bit_cast(__hip_bfloat16, (unsigned short)(w >> 16));
                }
            }
        }
    }
}

// ---------------- attention (R11 + K bank-conflict fix) --------------------
// grid 1024; (b,h) = blockIdx&127 (XCD-local), ib = blockIdx>>7.
// Wave owns TWO 16-row Q strips (32 rows); j-loop steps 64.
// Per wave-iter: 2 global_load_lds (K,V quarters) + 4 Er loads (rotated
// window) for 30 MFMAs; K/V fragments come from LDS (ds_read_b128).
__global__ __launch_bounds__(256) void attn_kernel(
    const __hip_bfloat16* __restrict__ Qs,
    const __hip_bfloat16* __restrict__ Kh,
    const __hip_bfloat16* __restrict__ Vt,   // bf16 view of Vti (same bytes)
    const __hip_bfloat16* __restrict__ Er,   // [2048][32] bf16 (row 2047 pad)
    float* __restrict__ out)                 // [B][S][E] f32
{
    const int tid  = threadIdx.x;
    const int wave = tid >> 6;
    const int lane = tid & 63;
    const int li   = lane & 15;
    const int quad = lane >> 4;

    const int c  = blockIdx.x & 127;
    const int b  = c >> 4;
    const int h  = c & 15;
    const int ib = blockIdx.x >> 7;          // 0..7
    const int i0 = ib * 128 + wave * 32;     // strip A rows i0.., B rows i0+16..

    const __hip_bfloat16* Qp  = Qs + (size_t)(b * Hh + h) * Ss * Dd;
    const __hip_bfloat16* Kp  = Kh + (size_t)(b * Hh + h) * Ss * Dd;
    const unsigned*       Vp32 = reinterpret_cast<const unsigned*>(Vt)
                               + (size_t)(b * Hh + h) * Dd * 512;

    __shared__ unsigned pb_lds[4][4][16 * 20];       // 20480 B
    __shared__ __align__(16) unsigned char kvbuf[8192];  // K 4KB @0, V 4KB @4096
    unsigned* pbA0 = pb_lds[wave][0];   // strip A cols 0-31
    unsigned* pbA1 = pb_lds[wave][1];   // strip A cols 32-63
    unsigned* pbB0 = pb_lds[wave][2];   // strip B cols 0-31
    unsigned* pbB1 = pb_lds[wave][3];   // strip B cols 32-63

    const bf16x8 qfA = ldg_frag(Qp + (i0      + li) * Dd + quad * 8);
    const bf16x8 qfB = ldg_frag(Qp + (i0 + 16 + li) * Dd + quad * 8);

    // loop-invariant: bpermute byte-addresses and SOURCE-side band-half
    // selector (see R7 comments). 1 bpermute per band value.
    int addr4[4];
    bool sel[4];
    #pragma unroll
    for (int r = 0; r < 4; ++r) {
        const int row = quad * 4 + r;
        addr4[r] = (16 * quad + ((li - row + 15) & 15)) * 4;
        sel[r]   = (li + row >= 15);       // this lane is a lower-block src
    }
    const int pbw = quad * 80 + li;        // pb write base (u32)
    const int pbr = li * 20 + quad * 4;    // pb read base (16B aligned)

    // staging addresses.
    // K quarter: lane l -> local row wave*16 + (l>>2); SOURCE 16B chunk
    // pre-XOR'd by s(row)=(l>>3)&3 so lds[row][c]=src[row][c^s(row)].
    const int krow  = wave * 16 + (lane >> 2);
    const int kcol8 = ((lane & 3) ^ ((lane >> 3) & 3)) * 8;  // bf16 elems
    char* kdst = (char*)kvbuf + wave * 1024;
    // V quarter: lane l -> local row wave*8 + (l>>3); source col-byte is
    // XOR-swizzled so the LINEAR LDS write realizes lds[row][cb^sw]=V[row][cb].
    const int vrow = wave * 8 + (lane >> 3);
    const int vcol4 = 4 * ((lane & 7) ^ ((lane >> 3) & 7));  // u32 within row
    char* vdst = (char*)kvbuf + 4096 + wave * 1024;
    const int swz = (li & 7) << 4;       // V read-side XOR
    const int kr  = (quad ^ ((li >> 1) & 3)) << 4;  // K read-side chunk

    f32x4 oA0 = f32x4{0,0,0,0}, oA1 = f32x4{0,0,0,0};
    f32x4 oB0 = f32x4{0,0,0,0}, oB1 = f32x4{0,0,0,0};
    f32x4 lsA = f32x4{0,0,0,0}, lsB = f32x4{0,0,0,0};
    const f32x4 zero = f32x4{0,0,0,0};

    bf16x8 ones;
    #pragma unroll
    for (int i = 0; i < 8; ++i) ones[i] = (short)0x3F80;   // bf16 1.0

    // Er rotation peel: window slides by 64 each iter; em'=e3, e0'=e4.
    const int rb0 = 1008 - i0;               // >= 16 for all i0
    bf16x8 em = ldg_frag(Er + (rb0 - 16 + li) * Dd + quad * 8);
    bf16x8 e0 = ldg_frag(Er + (rb0      + li) * Dd + quad * 8);

    for (int j0 = 0; j0 < Ss; j0 += 64) {
        // ---- stage K (64x32) + V (32x64, interleaved) tiles into LDS ----
        stage16(Kp + (size_t)(j0 + krow) * Dd + kcol8, kdst);
        stage16(Vp32 + (size_t)vrow * 512 + (j0 >> 1) + vcol4, vdst);

        // ---- Er loads (new window rows; overlap staging latency) ----
        const int rb = j0 - i0 + 1008;
        bf16x8 e1 = ldg_frag(Er + (rb + 16 + li) * Dd + quad * 8);
        bf16x8 e2 = ldg_frag(Er + (rb + 32 + li) * Dd + quad * 8);
        bf16x8 e3 = ldg_frag(Er + (rb + 48 + li) * Dd + quad * 8);
        bf16x8 e4 = ldg_frag(Er + (rb + 64 + li) * Dd + quad * 8);

        // implicit s_waitcnt vmcnt(0) lgkmcnt(0) + s_barrier: every wave's
        // staging loads have landed before anyone reads the tiles.
        __syncthreads();

        // ---- K/V fragments from LDS (both swizzle-read, ~2-way free) ----
        const char* Kb = (const char*)kvbuf;
        const char* Vb = (const char*)kvbuf + 4096;
        bf16x8 k0 = *reinterpret_cast<const bf16x8*>(Kb + (     li) * 64 + kr);
        bf16x8 k1 = *reinterpret_cast<const bf16x8*>(Kb + (16 + li) * 64 + kr);
        bf16x8 k2 = *reinterpret_cast<const bf16x8*>(Kb + (32 + li) * 64 + kr);
        bf16x8 k3 = *reinterpret_cast<const bf16x8*>(Kb + (48 + li) * 64 + kr);
        bf16x8 v0 = *reinterpret_cast<const bf16x8*>(Vb + (     li) * 128 + ((     quad * 16) ^ swz));
        bf16x8 v1 = *reinterpret_cast<const bf16x8*>(Vb + (16 + li) * 128 + ((     quad * 16) ^ swz));
        bf16x8 v2 = *reinterpret_cast<const bf16x8*>(Vb + (     li) * 128 + ((64 + quad * 16) ^ swz));
        bf16x8 v3 = *reinterpret_cast<const bf16x8*>(Vb + (16 + li) * 128 + ((64 + quad * 16) ^ swz));

        // ================= strip A (rows i0..i0+15) =================
        {
            __builtin_amdgcn_s_setprio(1);
            f32x4 s0 = __builtin_amdgcn_mfma_f32_16x16x32_bf16(qfA, k0, zero, 0, 0, 0);
            f32x4 s1 = __builtin_amdgcn_mfma_f32_16x16x32_bf16(qfA, k1, zero, 0, 0, 0);
            f32x4 s2 = __builtin_amdgcn_mfma_f32_16x16x32_bf16(qfA, k2, zero, 0, 0, 0);
            f32x4 s3 = __builtin_amdgcn_mfma_f32_16x16x32_bf16(qfA, k3, zero, 0, 0, 0);
            f32x4 q0 = __builtin_amdgcn_mfma_f32_16x16x32_bf16(qfA, e0, zero, 0, 0, 0);
            f32x4 q1 = __builtin_amdgcn_mfma_f32_16x16x32_bf16(qfA, e1, zero, 0, 0, 0);
            f32x4 q2 = __builtin_amdgcn_mfma_f32_16x16x32_bf16(qfA, e2, zero, 0, 0, 0);
            f32x4 q3 = __builtin_amdgcn_mfma_f32_16x16x32_bf16(qfA, e3, zero, 0, 0, 0);
            f32x4 q4 = __builtin_amdgcn_mfma_f32_16x16x32_bf16(qfA, e4, zero, 0, 0, 0);
            __builtin_amdgcn_s_setprio(0);
            float p0[4], p1[4], p2[4], p3[4];
            #pragma unroll
            for (int r = 0; r < 4; ++r) {
                float m0 = sel[r] ? q0[r] : q1[r];
                float m1 = sel[r] ? q1[r] : q2[r];
                float m2 = sel[r] ? q2[r] : q3[r];
                float m3 = sel[r] ? q3[r] : q4[r];
                p0[r] = EXP2F(s0[r] + bperm_f(addr4[r], m0));
                p1[r] = EXP2F(s1[r] + bperm_f(addr4[r], m1));
                p2[r] = EXP2F(s2[r] + bperm_f(addr4[r], m2));
                p3[r] = EXP2F(s3[r] + bperm_f(addr4[r], m3));
            }
            #pragma unroll
            for (int r = 0; r < 4; ++r) {
                pbA0[pbw + 20 * r] = pack_bf16(p0[r], p1[r]);
                pbA1[pbw + 20 * r] = pack_bf16(p2[r], p3[r]);
            }
            bf16x8 pf0 = *reinterpret_cast<const bf16x8*>(&pbA0[pbr]);
            bf16x8 pf1 = *reinterpret_cast<const bf16x8*>(&pbA1[pbr]);
            __builtin_amdgcn_s_setprio(1);
            oA0 = __builtin_amdgcn_mfma_f32_16x16x32_bf16(pf0, v0, oA0, 0, 0, 0);
            oA1 = __builtin_amdgcn_mfma_f32_16x16x32_bf16(pf0, v1, oA1, 0, 0, 0);
            oA0 = __builtin_amdgcn_mfma_f32_16x16x32_bf16(pf1, v2, oA0, 0, 0, 0);
            oA1 = __builtin_amdgcn_mfma_f32_16x16x32_bf16(pf1, v3, oA1, 0, 0, 0);
            lsA = __builtin_amdgcn_mfma_f32_16x16x32_bf16(pf0, ones, lsA, 0, 0, 0);
            lsA = __builtin_amdgcn_mfma_f32_16x16x32_bf16(pf1, ones, lsA, 0, 0, 0);
            __builtin_amdgcn_s_setprio(0);
        }

        // ================= strip B (rows i0+16..i0+31) ==============
        // strip B's band block n == strip A's block n-1: uses em,e0..e3.
        {
            __builtin_amdgcn_s_setprio(1);
            f32x4 s0 = __builtin_amdgcn_mfma_f32_16x16x32_bf16(qfB, k0, zero, 0, 0, 0);
            f32x4 s1 = __builtin_amdgcn_mfma_f32_16x16x32_bf16(qfB, k1, zero, 0, 0, 0);
            f32x4 s2 = __builtin_amdgcn_mfma_f32_16x16x32_bf16(qfB, k2, zero, 0, 0, 0);
            f32x4 s3 = __builtin_amdgcn_mfma_f32_16x16x32_bf16(qfB, k3, zero, 0, 0, 0);
            f32x4 q0 = __builtin_amdgcn_mfma_f32_16x16x32_bf16(qfB, em, zero, 0, 0, 0);
            f32x4 q1 = __builtin_amdgcn_mfma_f32_16x16x32_bf16(qfB, e0, zero, 0, 0, 0);
            f32x4 q2 = __builtin_amdgcn_mfma_f32_16x16x32_bf16(qfB, e1, zero, 0, 0, 0);
            f32x4 q3 = __builtin_amdgcn_mfma_f32_16x16x32_bf16(qfB, e2, zero, 0, 0, 0);
            f32x4 q4 = __builtin_amdgcn_mfma_f32_16x16x32_bf16(qfB, e3, zero, 0, 0, 0);
            __builtin_amdgcn_s_setprio(0);
            float p0[4], p1[4], p2[4], p3[4];
            #pragma unroll
            for (int r = 0; r < 4; ++r) {
                float m0 = sel[r] ? q0[r] : q1[r];
                float m1 = sel[r] ? q1[r] : q2[r];
                float m2 = sel[r] ? q2[r] : q3[r];
                float m3 = sel[r] ? q3[r] : q4[r];
                p0[r] = EXP2F(s0[r] + bperm_f(addr4[r], m0));
                p1[r] = EXP2F(s1[r] + bperm_f(addr4[r], m1));
                p2[r] = EXP2F(s2[r] + bperm_f(addr4[r], m2));
                p3[r] = EXP2F(s3[r] + bperm_f(addr4[r], m3));
            }
            #pragma unroll
            for (int r = 0; r < 4; ++r) {
                pbB0[pbw + 20 * r] = pack_bf16(p0[r], p1[r]);
                pbB1[pbw + 20 * r] = pack_bf16(p2[r], p3[r]);
            }
            bf16x8 pf0 = *reinterpret_cast<const bf16x8*>(&pbB0[pbr]);
            bf16x8 pf1 = *reinterpret_cast<const bf16x8*>(&pbB1[pbr]);
            __builtin_amdgcn_s_setprio(1);
            oB0 = __builtin_amdgcn_mfma_f32_16x16x32_bf16(pf0, v0, oB0, 0, 0, 0);
            oB1 = __builtin_amdgcn_mfma_f32_16x16x32_bf16(pf0, v1, oB1, 0, 0, 0);
            oB0 = __builtin_amdgcn_mfma_f32_16x16x32_bf16(pf1, v2, oB0, 0, 0, 0);
            oB1 = __builtin_amdgcn_mfma_f32_16x16x32_bf16(pf1, v3, oB1, 0, 0, 0);
            lsB = __builtin_amdgcn_mfma_f32_16x16x32_bf16(pf0, ones, lsB, 0, 0, 0);
            lsB = __builtin_amdgcn_mfma_f32_16x16x32_bf16(pf1, ones, lsB, 0, 0, 0);
            __builtin_amdgcn_s_setprio(0);
        }

        // rotate Er window; keep buffer safe for next iter's staging.
        em = e3;
        e0 = e4;
        __syncthreads();
    }

    // ones-MFMA accumulated exact row sums in the same C layout as oA/oB.
    #pragma unroll
    for (int r = 0; r < 4; ++r) {
        lsA[r] = 1.0f / lsA[r];
        lsB[r] = 1.0f / lsB[r];
    }
    #pragma unroll
    for (int r = 0; r < 4; ++r) {
        const int srowA = i0 + quad * 4 + r;
        float* opA = out + ((size_t)b * Ss + srowA) * Ee + h * Dd;
        opA[li]      = oA0[r] * lsA[r];
        opA[16 + li] = oA1[r] * lsA[r];
        float* opB = opA + 16 * Ee;          // srowA + 16
        opB[li]      = oB0[r] * lsB[r];
        opB[16 + li] = oB1[r] * lsB[r];
    }
}

extern "C" void kernel_launch(void* const* d_in, const int* in_sizes, int n_in,
                              void* d_out, int out_size, void* d_ws, size_t ws_size,
                              hipStream_t stream) {
    const float* x  = (const float*)d_in[0];
    const float* Wq = (const float*)d_in[1];
    const float* Wk = (const float*)d_in[2];
    const float* Wv = (const float*)d_in[3];
    const float* Er = (const float*)d_in[4];
    float* out = (float*)d_out;

    // ws layout (bf16 elements; all offsets 16B-aligned)
    __hip_bfloat16* xb  = reinterpret_cast<__hip_bfloat16*>(d_ws);
    __hip_bfloat16* wbb = xb  + (size_t)8192 * 512;
    __hip_bfloat16* erb = wbb + (size_t)1536 * 512;
    __hip_bfloat16* Qs  = erb + 65536;                  // row 2047 = pad
    __hip_bfloat16* Kh  = Qs  + (size_t)Bb * Hh * Ss * Dd;
    __hip_bfloat16* Vt  = Kh  + (size_t)Bb * Hh * Ss * Dd;

    convert_kernel<<<4929, 256, 0, stream>>>(x, Wq, Wk, Wv, Er, xb, wbb, erb);
    proj_kernel<<<dim3(6, 128), 256, 0, stream>>>(
        xb, wbb, Qs, Kh, reinterpret_cast<unsigned*>(Vt));
    attn_kernel<<<dim3(1024), 256, 0, stream>>>(Qs, Kh, Vt, erb, out);
}

// Round 8
// 162.760 us; speedup vs baseline: 1.2893x; 1.0248x over previous
//
#include <hip/hip_runtime.h>
#include <hip/hip_bf16.h>

// LocalAttn: B=8 S=1024 E=512 H=16 D=32, rel-pos bias, NO causal mask.
// f32 inputs / f32 output. Internals bf16 for MFMA.
// R14: double-buffered staging + counted vmcnt + ONE barrier/iter (T3/T4
// minimum-2-phase) on BOTH staged loops.
// attn: kvbuf[2]; per iter: Er loads -> vmcnt(4) (drains prev staging,
// keeps Er in flight) -> s_barrier -> ds_read buf[cur] -> stage buf[cur^1]
// -> compute. Staging hides under a full iter of MFMA+softmax; barriers
// halved. proj: smem[2]; vmcnt(0) -> barrier -> read -> stage next -> 16
// MFMAs. Order discipline: read-before-stage keeps skew-1 waves on the
// opposite buffer; asm("":::"memory") after stage pairs pins issue order
// (vmcnt counts depend on it); sched_barrier(0) per rule #18.
// Bytes/values/swizzles identical to R13 -> bit-identical output.

typedef short bf16x8 __attribute__((ext_vector_type(8)));   // 8 bf16 (4 VGPRs)
typedef float f32x4 __attribute__((ext_vector_type(4)));
typedef unsigned int u32x2 __attribute__((ext_vector_type(2)));
typedef unsigned int u32x4 __attribute__((ext_vector_type(4)));

#if __has_builtin(__builtin_amdgcn_exp2f)
#define EXP2F(x) __builtin_amdgcn_exp2f(x)
#else
#define EXP2F(x) exp2f(x)
#endif

constexpr int Bb = 8, Ss = 1024, Ee = 512, Hh = 16, Dd = 32;
// log2(e)/sqrt(32): folds the 1/sqrt(D) softmax scale and exp->exp2 into Q.
#define QSCALE 0.25503486f

__device__ __forceinline__ bf16x8 ldg_frag(const __hip_bfloat16* p) {
    return *reinterpret_cast<const bf16x8*>(p);
}

// hardware packed f32->bf16 (RNE), lo in [15:0], hi in [31:16].
__device__ __forceinline__ unsigned pack_bf16(float lo, float hi) {
    unsigned r;
    asm("v_cvt_pk_bf16_f32 %0, %1, %2" : "=v"(r) : "v"(lo), "v"(hi));
    return r;
}

__device__ __forceinline__ float bperm_f(int addr, float v) {
    return __builtin_bit_cast(float,
        __builtin_amdgcn_ds_bpermute(addr, __builtin_bit_cast(int, v)));
}

// async global->LDS, 16B/lane; LDS dest = wave-uniform base + lane*16.
__device__ __forceinline__ void stage16(const void* g, void* l) {
    typedef const __attribute__((address_space(1))) char gch;
    typedef __attribute__((address_space(3))) char lch;
    __builtin_amdgcn_global_load_lds((gch*)g, (lch*)l, 16, 0, 0);
}

// ---------------- f32 -> bf16 conversion into workspace -------------------
__global__ __launch_bounds__(256) void convert_kernel(
    const float* __restrict__ x,  const float* __restrict__ wq,
    const float* __restrict__ wk, const float* __restrict__ wv,
    const float* __restrict__ er,
    __hip_bfloat16* __restrict__ xb, __hip_bfloat16* __restrict__ wb,
    __hip_bfloat16* __restrict__ erb)
{
    const int GX = 1048576, GW = 65536, GE = 16376;  // in float4 groups
    int g = blockIdx.x * 256 + threadIdx.x;
    if (g >= GX + 3 * GW + GE) return;
    const float* src;
    __hip_bfloat16* dst;
    int rel;
    if (g < GX)               { src = x;  dst = xb;          rel = g; }
    else if (g < GX +   GW)   { src = wq; dst = wb;          rel = g - GX; }
    else if (g < GX + 2*GW)   { src = wk; dst = wb + 262144; rel = g - GX - GW; }
    else if (g < GX + 3*GW)   { src = wv; dst = wb + 524288; rel = g - GX - 2*GW; }
    else                      { src = er; dst = erb;         rel = g - GX - 3*GW; }
    const float4 v = *reinterpret_cast<const float4*>(src + (size_t)rel * 4);
    u32x2 pk;
    pk[0] = pack_bf16(v.x, v.y);
    pk[1] = pack_bf16(v.z, v.w);
    *reinterpret_cast<u32x2*>(dst + (size_t)rel * 4) = pk;
}

// ---------------- projection: Q/K/V = x @ W^T ------------------------------
// grid (6,128): WG = 64 rows x 256 cols of [Q|K|V]; wave = 64x64.
// Double-buffered m97 staging: per K-step stage A(64x32)+B(256x32) for
// step k+1 while MFMAs run on step k; 1 barrier + vmcnt(0) per step.
__global__ __launch_bounds__(256) void proj_kernel(
    const __hip_bfloat16* __restrict__ xb,   // [8192][512]
    const __hip_bfloat16* __restrict__ wb,   // [1536][512]
    __hip_bfloat16* __restrict__ Qs,   // [B][H][S][D], scaled by QSCALE
    __hip_bfloat16* __restrict__ Kh,   // [B][H][S][D]
    unsigned* __restrict__ Vt32)       // [B][H][D][512 u32] interleaved
{
    const int tid  = threadIdx.x;
    const int wave = tid >> 6;
    const int lane = tid & 63;
    const int li   = lane & 15;
    const int quad = lane >> 4;

    const int m0    = blockIdx.y * 64;
    const int nbase = blockIdx.x * 256 + wave * 64;   // multiple of 64

    __shared__ __align__(16) char smem[2][20480];   // A 4KB @0, B 16KB @4096

    f32x4 acc[4][4];
    #pragma unroll
    for (int rf = 0; rf < 4; ++rf)
        #pragma unroll
        for (int t = 0; t < 4; ++t) acc[rf][t] = f32x4{0.f, 0.f, 0.f, 0.f};

    // staging: lane l covers row (l>>2) of its 16-row group, 16B chunk
    // (l&3) of the 64B k-slice; source chunk pre-XOR'd by s(row)=(l>>3)&3.
    const int srow   = lane >> 2;
    const int schunk = ((lane & 3) ^ ((lane >> 3) & 3)) << 4;   // bytes
    const char* Asrc = (const char*)xb
        + (((size_t)(m0 + wave * 16 + srow)) << 10) + schunk;   // row*1024B
    const char* Bsrc = (const char*)wb
        + (((size_t)(blockIdx.x * 256 + wave * 64 + srow)) << 10) + schunk;

    // read-side chunk: quad ^ s(row); s(row)=(li>>1)&3 for all frag rows.
    const int rchunk = (quad ^ ((li >> 1) & 3)) << 4;

    // prologue: stage k=0 into buf 0.
    {
        char* N = smem[0];
        stage16(Asrc,         N + wave * 1024);
        stage16(Bsrc,         N + 4096 + wave * 4096);
        stage16(Bsrc + 16384, N + 4096 + wave * 4096 + 1024);
        stage16(Bsrc + 32768, N + 4096 + wave * 4096 + 2048);
        stage16(Bsrc + 49152, N + 4096 + wave * 4096 + 3072);
        asm volatile("" ::: "memory");
    }

    int cur = 0;
    for (int k0 = 0; k0 < Ee; k0 += 32) {
        __builtin_amdgcn_sched_barrier(0);
        asm volatile("s_waitcnt vmcnt(0)" ::: "memory");
        __builtin_amdgcn_s_barrier();
        asm volatile("" ::: "memory");
        __builtin_amdgcn_sched_barrier(0);

        const char* S = smem[cur];
        bf16x8 a[4], bfr[4];
        #pragma unroll
        for (int rf = 0; rf < 4; ++rf)
            a[rf] = *reinterpret_cast<const bf16x8*>(
                S + (rf * 16 + li) * 64 + rchunk);
        #pragma unroll
        for (int t = 0; t < 4; ++t)
            bfr[t] = *reinterpret_cast<const bf16x8*>(
                S + 4096 + (wave * 64 + t * 16 + li) * 64 + rchunk);

        // stage next K-step into the other buffer (wrap: restage 0, unused)
        {
            const int kb = ((k0 + 32) & 511) * 2;      // byte offset in row
            char* N = smem[cur ^ 1];
            stage16(Asrc + kb,         N + wave * 1024);
            stage16(Bsrc + kb,         N + 4096 + wave * 4096);
            stage16(Bsrc + kb + 16384, N + 4096 + wave * 4096 + 1024);
            stage16(Bsrc + kb + 32768, N + 4096 + wave * 4096 + 2048);
            stage16(Bsrc + kb + 49152, N + 4096 + wave * 4096 + 3072);
            asm volatile("" ::: "memory");
        }

        #pragma unroll
        for (int rf = 0; rf < 4; ++rf)
            #pragma unroll
            for (int t = 0; t < 4; ++t)
                acc[rf][t] = __builtin_amdgcn_mfma_f32_16x16x32_bf16(
                    a[rf], bfr[t], acc[rf][t], 0, 0, 0);
        cur ^= 1;
    }

    // epilogue. C layout: col = li, row = quad*4 + reg.
    const int mat = nbase >> 9;        // 0=Q 1=K 2=V (uniform per wave)
    const int nn0 = nbase & 511;
    const int bb  = m0 >> 10;          // 64-row block never straddles b
    const int sb  = m0 & 1023;
    if (mat == 2) {
        #pragma unroll
        for (int t = 0; t < 4; ++t) {
            int nn = nn0 + t * 16 + li;
            int h = nn >> 5, d = nn & 31;
            size_t base = ((size_t)(bb * Hh + h) * Dd + d) * 512
                        + (sb >> 5) * 16 + quad * 4;
            #pragma unroll
            for (int p = 0; p < 2; ++p) {      // rf pair (2p, 2p+1)
                u32x4 pk;
                #pragma unroll
                for (int r = 0; r < 4; ++r)
                    pk[r] = pack_bf16(acc[2*p][t][r], acc[2*p+1][t][r]);
                *reinterpret_cast<u32x4*>(Vt32 + base + (size_t)p * 16) = pk;
            }
        }
    } else {
        __hip_bfloat16* dst = (mat == 0) ? Qs : Kh;
        const float sc = (mat == 0) ? QSCALE : 1.0f;
        #pragma unroll
        for (int rf = 0; rf < 4; ++rf) {
            const int srw = sb + rf * 16 + quad * 4;
            #pragma unroll
            for (int t = 0; t < 4; ++t) {
                int nn = nn0 + t * 16 + li;
                int h = nn >> 5, d = nn & 31;
                size_t base = ((size_t)(bb * Hh + h) * Ss + srw) * Dd + d;
                #pragma unroll
                for (int r = 0; r < 4; r += 2) {
                    unsigned w = pack_bf16(acc[rf][t][r]     * sc,
                                           acc[rf][t][r + 1] * sc);
                    dst[base + (size_t)r * Dd] =
                        __builtin_bit_cast(__hip_bfloat16, (unsigned short)(w & 0xffffu));
                    dst[base + (size_t)(r + 1) * Dd] =
                        __builtin_bit_cast(__hip_bfloat16, (unsigned short)(w >> 16));
                }
            }
        }
    }
}

// ---------------- attention (R13 + kv double-buffer, 1 barrier/iter) -------
// grid 1024; (b,h) = blockIdx&127 (XCD-local), ib = blockIdx>>7.
// Wave owns TWO 16-row Q strips (32 rows); j-loop steps 64.
// Iter: Er(4) -> vmcnt(4) -> s_barrier -> ds_read buf[cur] ->
// stage buf[cur^1] (j0+64) -> compute strips A,B.
__global__ __launch_bounds__(256) void attn_kernel(
    const __hip_bfloat16* __restrict__ Qs,
    const __hip_bfloat16* __restrict__ Kh,
    const __hip_bfloat16* __restrict__ Vt,   // bf16 view of Vti (same bytes)
    const __hip_bfloat16* __restrict__ Er,   // [2048][32] bf16 (row 2047 pad)
    float* __restrict__ out)                 // [B][S][E] f32
{
    const int tid  = threadIdx.x;
    const int wave = tid >> 6;
    const int lane = tid & 63;
    const int li   = lane & 15;
    const int quad = lane >> 4;

    const int c  = blockIdx.x & 127;
    const int b  = c >> 4;
    const int h  = c & 15;
    const int ib = blockIdx.x >> 7;          // 0..7
    const int i0 = ib * 128 + wave * 32;     // strip A rows i0.., B rows i0+16..

    const __hip_bfloat16* Qp  = Qs + (size_t)(b * Hh + h) * Ss * Dd;
    const __hip_bfloat16* Kp  = Kh + (size_t)(b * Hh + h) * Ss * Dd;
    const unsigned*       Vp32 = reinterpret_cast<const unsigned*>(Vt)
                               + (size_t)(b * Hh + h) * Dd * 512;

    __shared__ unsigned pb_lds[4][4][16 * 20];           // 20480 B
    __shared__ __align__(16) unsigned char kvbuf[2][8192];  // K @0, V @4096
    unsigned* pbA0 = pb_lds[wave][0];   // strip A cols 0-31
    unsigned* pbA1 = pb_lds[wave][1];   // strip A cols 32-63
    unsigned* pbB0 = pb_lds[wave][2];   // strip B cols 0-31
    unsigned* pbB1 = pb_lds[wave][3];   // strip B cols 32-63

    // staging addresses (R13 verbatim).
    const int krow  = wave * 16 + (lane >> 2);
    const int kcol8 = ((lane & 3) ^ ((lane >> 3) & 3)) * 8;  // bf16 elems
    const int vrow = wave * 8 + (lane >> 3);
    const int vcol4 = 4 * ((lane & 7) ^ ((lane >> 3) & 7));  // u32 within row
    const int swz = (li & 7) << 4;       // V read-side XOR
    const int kr  = (quad ^ ((li >> 1) & 3)) << 4;  // K read-side chunk

    // prologue: stage j=0 into buf 0.
    stage16(Kp + (size_t)krow * Dd + kcol8, (char*)kvbuf[0] + wave * 1024);
    stage16(Vp32 + (size_t)vrow * 512 + vcol4,
            (char*)kvbuf[0] + 4096 + wave * 1024);
    asm volatile("" ::: "memory");

    const bf16x8 qfA = ldg_frag(Qp + (i0      + li) * Dd + quad * 8);
    const bf16x8 qfB = ldg_frag(Qp + (i0 + 16 + li) * Dd + quad * 8);

    // loop-invariant: bpermute byte-addresses and SOURCE-side band-half
    // selector (see R7 comments). 1 bpermute per band value.
    int addr4[4];
    bool sel[4];
    #pragma unroll
    for (int r = 0; r < 4; ++r) {
        const int row = quad * 4 + r;
        addr4[r] = (16 * quad + ((li - row + 15) & 15)) * 4;
        sel[r]   = (li + row >= 15);       // this lane is a lower-block src
    }
    const int pbw = quad * 80 + li;        // pb write base (u32)
    const int pbr = li * 20 + quad * 4;    // pb read base (16B aligned)

    f32x4 oA0 = f32x4{0,0,0,0}, oA1 = f32x4{0,0,0,0};
    f32x4 oB0 = f32x4{0,0,0,0}, oB1 = f32x4{0,0,0,0};
    f32x4 lsA = f32x4{0,0,0,0}, lsB = f32x4{0,0,0,0};
    const f32x4 zero = f32x4{0,0,0,0};

    bf16x8 ones;
    #pragma unroll
    for (int i = 0; i < 8; ++i) ones[i] = (short)0x3F80;   // bf16 1.0

    // Er rotation peel: window slides by 64 each iter; em'=e3, e0'=e4.
    const int rb0 = 1008 - i0;               // >= 16 for all i0
    bf16x8 em = ldg_frag(Er + (rb0 - 16 + li) * Dd + quad * 8);
    bf16x8 e0 = ldg_frag(Er + (rb0      + li) * Dd + quad * 8);

    int cur = 0;
    for (int j0 = 0; j0 < Ss; j0 += 64) {
        // ---- Er loads (stay in flight across the vmcnt below) ----
        const int rb = j0 - i0 + 1008;
        bf16x8 e1 = ldg_frag(Er + (rb + 16 + li) * Dd + quad * 8);
        bf16x8 e2 = ldg_frag(Er + (rb + 32 + li) * Dd + quad * 8);
        bf16x8 e3 = ldg_frag(Er + (rb + 48 + li) * Dd + quad * 8);
        bf16x8 e4 = ldg_frag(Er + (rb + 64 + li) * Dd + quad * 8);

        // drain my 2 staging ops for buf[cur] (issued last iter), keep the
        // 4 Er loads in flight; barrier makes it block-wide.
        __builtin_amdgcn_sched_barrier(0);
        asm volatile("s_waitcnt vmcnt(4)" ::: "memory");
        __builtin_amdgcn_s_barrier();
        asm volatile("" ::: "memory");
        __builtin_amdgcn_sched_barrier(0);

        // ---- K/V fragments from LDS buf[cur] ----
        const char* Kb = (const char*)kvbuf[cur];
        const char* Vb = Kb + 4096;
        bf16x8 k0 = *reinterpret_cast<const bf16x8*>(Kb + (     li) * 64 + kr);
        bf16x8 k1 = *reinterpret_cast<const bf16x8*>(Kb + (16 + li) * 64 + kr);
        bf16x8 k2 = *reinterpret_cast<const bf16x8*>(Kb + (32 + li) * 64 + kr);
        bf16x8 k3 = *reinterpret_cast<const bf16x8*>(Kb + (48 + li) * 64 + kr);
        bf16x8 v0 = *reinterpret_cast<const bf16x8*>(Vb + (     li) * 128 + ((     quad * 16) ^ swz));
        bf16x8 v1 = *reinterpret_cast<const bf16x8*>(Vb + (16 + li) * 128 + ((     quad * 16) ^ swz));
        bf16x8 v2 = *reinterpret_cast<const bf16x8*>(Vb + (     li) * 128 + ((64 + quad * 16) ^ swz));
        bf16x8 v3 = *reinterpret_cast<const bf16x8*>(Vb + (16 + li) * 128 + ((64 + quad * 16) ^ swz));

        // ---- stage next j-tile into buf[cur^1] (lands under compute) ----
        {
            const int jn = (j0 + 64) & 1023;     // wrap: restage j=0, unused
            char* N = (char*)kvbuf[cur ^ 1];
            stage16(Kp + (size_t)(jn + krow) * Dd + kcol8, N + wave * 1024);
            stage16(Vp32 + (size_t)vrow * 512 + (jn >> 1) + vcol4,
                    N + 4096 + wave * 1024);
            asm volatile("" ::: "memory");
        }

        // ================= strip A (rows i0..i0+15) =================
        {
            __builtin_amdgcn_s_setprio(1);
            f32x4 s0 = __builtin_amdgcn_mfma_f32_16x16x32_bf16(qfA, k0, zero, 0, 0, 0);
            f32x4 s1 = __builtin_amdgcn_mfma_f32_16x16x32_bf16(qfA, k1, zero, 0, 0, 0);
            f32x4 s2 = __builtin_amdgcn_mfma_f32_16x16x32_bf16(qfA, k2, zero, 0, 0, 0);
            f32x4 s3 = __builtin_amdgcn_mfma_f32_16x16x32_bf16(qfA, k3, zero, 0, 0, 0);
            f32x4 q0 = __builtin_amdgcn_mfma_f32_16x16x32_bf16(qfA, e0, zero, 0, 0, 0);
            f32x4 q1 = __builtin_amdgcn_mfma_f32_16x16x32_bf16(qfA, e1, zero, 0, 0, 0);
            f32x4 q2 = __builtin_amdgcn_mfma_f32_16x16x32_bf16(qfA, e2, zero, 0, 0, 0);
            f32x4 q3 = __builtin_amdgcn_mfma_f32_16x16x32_bf16(qfA, e3, zero, 0, 0, 0);
            f32x4 q4 = __builtin_amdgcn_mfma_f32_16x16x32_bf16(qfA, e4, zero, 0, 0, 0);
            __builtin_amdgcn_s_setprio(0);
            float p0[4], p1[4], p2[4], p3[4];
            #pragma unroll
            for (int r = 0; r < 4; ++r) {
                float m0 = sel[r] ? q0[r] : q1[r];
                float m1 = sel[r] ? q1[r] : q2[r];
                float m2 = sel[r] ? q2[r] : q3[r];
                float m3 = sel[r] ? q3[r] : q4[r];
                p0[r] = EXP2F(s0[r] + bperm_f(addr4[r], m0));
                p1[r] = EXP2F(s1[r] + bperm_f(addr4[r], m1));
                p2[r] = EXP2F(s2[r] + bperm_f(addr4[r], m2));
                p3[r] = EXP2F(s3[r] + bperm_f(addr4[r], m3));
            }
            #pragma unroll
            for (int r = 0; r < 4; ++r) {
                pbA0[pbw + 20 * r] = pack_bf16(p0[r], p1[r]);
                pbA1[pbw + 20 * r] = pack_bf16(p2[r], p3[r]);
            }
            bf16x8 pf0 = *reinterpret_cast<const bf16x8*>(&pbA0[pbr]);
            bf16x8 pf1 = *reinterpret_cast<const bf16x8*>(&pbA1[pbr]);
            __builtin_amdgcn_s_setprio(1);
            oA0 = __builtin_amdgcn_mfma_f32_16x16x32_bf16(pf0, v0, oA0, 0, 0, 0);
            oA1 = __builtin_amdgcn_mfma_f32_16x16x32_bf16(pf0, v1, oA1, 0, 0, 0);
            oA0 = __builtin_amdgcn_mfma_f32_16x16x32_bf16(pf1, v2, oA0, 0, 0, 0);
            oA1 = __builtin_amdgcn_mfma_f32_16x16x32_bf16(pf1, v3, oA1, 0, 0, 0);
            lsA = __builtin_amdgcn_mfma_f32_16x16x32_bf16(pf0, ones, lsA, 0, 0, 0);
            lsA = __builtin_amdgcn_mfma_f32_16x16x32_bf16(pf1, ones, lsA, 0, 0, 0);
            __builtin_amdgcn_s_setprio(0);
        }

        // ================= strip B (rows i0+16..i0+31) ==============
        // strip B's band block n == strip A's block n-1: uses em,e0..e3.
        {
            __builtin_amdgcn_s_setprio(1);
            f32x4 s0 = __builtin_amdgcn_mfma_f32_16x16x32_bf16(qfB, k0, zero, 0, 0, 0);
            f32x4 s1 = __builtin_amdgcn_mfma_f32_16x16x32_bf16(qfB, k1, zero, 0, 0, 0);
            f32x4 s2 = __builtin_amdgcn_mfma_f32_16x16x32_bf16(qfB, k2, zero, 0, 0, 0);
            f32x4 s3 = __builtin_amdgcn_mfma_f32_16x16x32_bf16(qfB, k3, zero, 0, 0, 0);
            f32x4 q0 = __builtin_amdgcn_mfma_f32_16x16x32_bf16(qfB, em, zero, 0, 0, 0);
            f32x4 q1 = __builtin_amdgcn_mfma_f32_16x16x32_bf16(qfB, e0, zero, 0, 0, 0);
            f32x4 q2 = __builtin_amdgcn_mfma_f32_16x16x32_bf16(qfB, e1, zero, 0, 0, 0);
            f32x4 q3 = __builtin_amdgcn_mfma_f32_16x16x32_bf16(qfB, e2, zero, 0, 0, 0);
            f32x4 q4 = __builtin_amdgcn_mfma_f32_16x16x32_bf16(qfB, e3, zero, 0, 0, 0);
            __builtin_amdgcn_s_setprio(0);
            float p0[4], p1[4], p2[4], p3[4];
            #pragma unroll
            for (int r = 0; r < 4; ++r) {
                float m0 = sel[r] ? q0[r] : q1[r];
                float m1 = sel[r] ? q1[r] : q2[r];
                float m2 = sel[r] ? q2[r] : q3[r];
                float m3 = sel[r] ? q3[r] : q4[r];
                p0[r] = EXP2F(s0[r] + bperm_f(addr4[r], m0));
                p1[r] = EXP2F(s1[r] + bperm_f(addr4[r], m1));
                p2[r] = EXP2F(s2[r] + bperm_f(addr4[r], m2));
                p3[r] = EXP2F(s3[r] + bperm_f(addr4[r], m3));
            }
            #pragma unroll
            for (int r = 0; r < 4; ++r) {
                pbB0[pbw + 20 * r] = pack_bf16(p0[r], p1[r]);
                pbB1[pbw + 20 * r] = pack_bf16(p2[r], p3[r]);
            }
            bf16x8 pf0 = *reinterpret_cast<const bf16x8*>(&pbB0[pbr]);
            bf16x8 pf1 = *reinterpret_cast<const bf16x8*>(&pbB1[pbr]);
            __builtin_amdgcn_s_setprio(1);
            oB0 = __builtin_amdgcn_mfma_f32_16x16x32_bf16(pf0, v0, oB0, 0, 0, 0);
            oB1 = __builtin_amdgcn_mfma_f32_16x16x32_bf16(pf0, v1, oB1, 0, 0, 0);
            oB0 = __builtin_amdgcn_mfma_f32_16x16x32_bf16(pf1, v2, oB0, 0, 0, 0);
            oB1 = __builtin_amdgcn_mfma_f32_16x16x32_bf16(pf1, v3, oB1, 0, 0, 0);
            lsB = __builtin_amdgcn_mfma_f32_16x16x32_bf16(pf0, ones, lsB, 0, 0, 0);
            lsB = __builtin_amdgcn_mfma_f32_16x16x32_bf16(pf1, ones, lsB, 0, 0, 0);
            __builtin_amdgcn_s_setprio(0);
        }

        // rotate Er window; flip buffers.
        em = e3;
        e0 = e4;
        cur ^= 1;
    }

    // ones-MFMA accumulated exact row sums in the same C layout as oA/oB.
    #pragma unroll
    for (int r = 0; r < 4; ++r) {
        lsA[r] = 1.0f / lsA[r];
        lsB[r] = 1.0f / lsB[r];
    }
    #pragma unroll
    for (int r = 0; r < 4; ++r) {
        const int srowA = i0 + quad * 4 + r;
        float* opA = out + ((size_t)b * Ss + srowA) * Ee + h * Dd;
        opA[li]      = oA0[r] * lsA[r];
        opA[16 + li] = oA1[r] * lsA[r];
        float* opB = opA + 16 * Ee;          // srowA + 16
        opB[li]      = oB0[r] * lsB[r];
        opB[16 + li] = oB1[r] * lsB[r];
    }
}

extern "C" void kernel_launch(void* const* d_in, const int* in_sizes, int n_in,
                              void* d_out, int out_size, void* d_ws, size_t ws_size,
                              hipStream_t stream) {
    const float* x  = (const float*)d_in[0];
    const float* Wq = (const float*)d_in[1];
    const float* Wk = (const float*)d_in[2];
    const float* Wv = (const float*)d_in[3];
    const float* Er = (const float*)d_in[4];
    float* out = (float*)d_out;

    // ws layout (bf16 elements; all offsets 16B-aligned)
    __hip_bfloat16* xb  = reinterpret_cast<__hip_bfloat16*>(d_ws);
    __hip_bfloat16* wbb = xb  + (size_t)8192 * 512;
    __hip_bfloat16* erb = wbb + (size_t)1536 * 512;
    __hip_bfloat16* Qs  = erb + 65536;                  // row 2047 = pad
    __hip_bfloat16* Kh  = Qs  + (size_t)Bb * Hh * Ss * Dd;
    __hip_bfloat16* Vt  = Kh  + (size_t)Bb * Hh * Ss * Dd;

    convert_kernel<<<4929, 256, 0, stream>>>(x, Wq, Wk, Wv, Er, xb, wbb, erb);
    proj_kernel<<<dim3(6, 128), 256, 0, stream>>>(
        xb, wbb, Qs, Kh, reinterpret_cast<unsigned*>(Vt));
    attn_kernel<<<dim3(1024), 256, 0, stream>>>(Qs, Kh, Vt, erb, out);
}

// Round 9
// 161.348 us; speedup vs baseline: 1.3006x; 1.0088x over previous
//
#include <hip/hip_runtime.h>
#include <hip/hip_bf16.h>

// LocalAttn: B=8 S=1024 E=512 H=16 D=32, rel-pos bias, NO causal mask.
// f32 inputs / f32 output. Internals bf16 for MFMA.
// R15: attn deferred-PV phase order: QK_A -> sm_A(pbA) -> QK_B -> sm_B(pbB)
// -> {pbA+pbB reads, 12 PV MFMAs in one burst}. pbA's LDS write->read gap
// now spans strip B's QK+softmax (~400cyc, was ~40) -> kills the lgkm
// stall before PV_A; PV burst overlaps next-iter Er issue. Register peak
// UNCHANGED (v0..v3 already live through strip B; pbA is in LDS; strip A
// s/q freed before strip B's set) -- the R8 spill trap does not apply.
// proj/convert UNCHANGED from R14 (control).
// Ledger: VALU diet -2.8%, reg-prefetch spill, 1-strip +22% DS (R12),
// 4-strip ~183 VGPR spill, band skew provably needs per-element shift.

typedef short bf16x8 __attribute__((ext_vector_type(8)));   // 8 bf16 (4 VGPRs)
typedef float f32x4 __attribute__((ext_vector_type(4)));
typedef unsigned int u32x2 __attribute__((ext_vector_type(2)));
typedef unsigned int u32x4 __attribute__((ext_vector_type(4)));

#if __has_builtin(__builtin_amdgcn_exp2f)
#define EXP2F(x) __builtin_amdgcn_exp2f(x)
#else
#define EXP2F(x) exp2f(x)
#endif

constexpr int Bb = 8, Ss = 1024, Ee = 512, Hh = 16, Dd = 32;
// log2(e)/sqrt(32): folds the 1/sqrt(D) softmax scale and exp->exp2 into Q.
#define QSCALE 0.25503486f

__device__ __forceinline__ bf16x8 ldg_frag(const __hip_bfloat16* p) {
    return *reinterpret_cast<const bf16x8*>(p);
}

// hardware packed f32->bf16 (RNE), lo in [15:0], hi in [31:16].
__device__ __forceinline__ unsigned pack_bf16(float lo, float hi) {
    unsigned r;
    asm("v_cvt_pk_bf16_f32 %0, %1, %2" : "=v"(r) : "v"(lo), "v"(hi));
    return r;
}

__device__ __forceinline__ float bperm_f(int addr, float v) {
    return __builtin_bit_cast(float,
        __builtin_amdgcn_ds_bpermute(addr, __builtin_bit_cast(int, v)));
}

// async global->LDS, 16B/lane; LDS dest = wave-uniform base + lane*16.
__device__ __forceinline__ void stage16(const void* g, void* l) {
    typedef const __attribute__((address_space(1))) char gch;
    typedef __attribute__((address_space(3))) char lch;
    __builtin_amdgcn_global_load_lds((gch*)g, (lch*)l, 16, 0, 0);
}

// ---------------- f32 -> bf16 conversion into workspace -------------------
__global__ __launch_bounds__(256) void convert_kernel(
    const float* __restrict__ x,  const float* __restrict__ wq,
    const float* __restrict__ wk, const float* __restrict__ wv,
    const float* __restrict__ er,
    __hip_bfloat16* __restrict__ xb, __hip_bfloat16* __restrict__ wb,
    __hip_bfloat16* __restrict__ erb)
{
    const int GX = 1048576, GW = 65536, GE = 16376;  // in float4 groups
    int g = blockIdx.x * 256 + threadIdx.x;
    if (g >= GX + 3 * GW + GE) return;
    const float* src;
    __hip_bfloat16* dst;
    int rel;
    if (g < GX)               { src = x;  dst = xb;          rel = g; }
    else if (g < GX +   GW)   { src = wq; dst = wb;          rel = g - GX; }
    else if (g < GX + 2*GW)   { src = wk; dst = wb + 262144; rel = g - GX - GW; }
    else if (g < GX + 3*GW)   { src = wv; dst = wb + 524288; rel = g - GX - 2*GW; }
    else                      { src = er; dst = erb;         rel = g - GX - 3*GW; }
    const float4 v = *reinterpret_cast<const float4*>(src + (size_t)rel * 4);
    u32x2 pk;
    pk[0] = pack_bf16(v.x, v.y);
    pk[1] = pack_bf16(v.z, v.w);
    *reinterpret_cast<u32x2*>(dst + (size_t)rel * 4) = pk;
}

// ---------------- projection: Q/K/V = x @ W^T ------------------------------
// grid (6,128): WG = 64 rows x 256 cols of [Q|K|V]; wave = 64x64.
// Double-buffered m97 staging: per K-step stage A(64x32)+B(256x32) for
// step k+1 while MFMAs run on step k; 1 barrier + vmcnt(0) per step.
__global__ __launch_bounds__(256) void proj_kernel(
    const __hip_bfloat16* __restrict__ xb,   // [8192][512]
    const __hip_bfloat16* __restrict__ wb,   // [1536][512]
    __hip_bfloat16* __restrict__ Qs,   // [B][H][S][D], scaled by QSCALE
    __hip_bfloat16* __restrict__ Kh,   // [B][H][S][D]
    unsigned* __restrict__ Vt32)       // [B][H][D][512 u32] interleaved
{
    const int tid  = threadIdx.x;
    const int wave = tid >> 6;
    const int lane = tid & 63;
    const int li   = lane & 15;
    const int quad = lane >> 4;

    const int m0    = blockIdx.y * 64;
    const int nbase = blockIdx.x * 256 + wave * 64;   // multiple of 64

    __shared__ __align__(16) char smem[2][20480];   // A 4KB @0, B 16KB @4096

    f32x4 acc[4][4];
    #pragma unroll
    for (int rf = 0; rf < 4; ++rf)
        #pragma unroll
        for (int t = 0; t < 4; ++t) acc[rf][t] = f32x4{0.f, 0.f, 0.f, 0.f};

    // staging: lane l covers row (l>>2) of its 16-row group, 16B chunk
    // (l&3) of the 64B k-slice; source chunk pre-XOR'd by s(row)=(l>>3)&3.
    const int srow   = lane >> 2;
    const int schunk = ((lane & 3) ^ ((lane >> 3) & 3)) << 4;   // bytes
    const char* Asrc = (const char*)xb
        + (((size_t)(m0 + wave * 16 + srow)) << 10) + schunk;   // row*1024B
    const char* Bsrc = (const char*)wb
        + (((size_t)(blockIdx.x * 256 + wave * 64 + srow)) << 10) + schunk;

    // read-side chunk: quad ^ s(row); s(row)=(li>>1)&3 for all frag rows.
    const int rchunk = (quad ^ ((li >> 1) & 3)) << 4;

    // prologue: stage k=0 into buf 0.
    {
        char* N = smem[0];
        stage16(Asrc,         N + wave * 1024);
        stage16(Bsrc,         N + 4096 + wave * 4096);
        stage16(Bsrc + 16384, N + 4096 + wave * 4096 + 1024);
        stage16(Bsrc + 32768, N + 4096 + wave * 4096 + 2048);
        stage16(Bsrc + 49152, N + 4096 + wave * 4096 + 3072);
        asm volatile("" ::: "memory");
    }

    int cur = 0;
    for (int k0 = 0; k0 < Ee; k0 += 32) {
        __builtin_amdgcn_sched_barrier(0);
        asm volatile("s_waitcnt vmcnt(0)" ::: "memory");
        __builtin_amdgcn_s_barrier();
        asm volatile("" ::: "memory");
        __builtin_amdgcn_sched_barrier(0);

        const char* S = smem[cur];
        bf16x8 a[4], bfr[4];
        #pragma unroll
        for (int rf = 0; rf < 4; ++rf)
            a[rf] = *reinterpret_cast<const bf16x8*>(
                S + (rf * 16 + li) * 64 + rchunk);
        #pragma unroll
        for (int t = 0; t < 4; ++t)
            bfr[t] = *reinterpret_cast<const bf16x8*>(
                S + 4096 + (wave * 64 + t * 16 + li) * 64 + rchunk);

        // stage next K-step into the other buffer (wrap: restage 0, unused)
        {
            const int kb = ((k0 + 32) & 511) * 2;      // byte offset in row
            char* N = smem[cur ^ 1];
            stage16(Asrc + kb,         N + wave * 1024);
            stage16(Bsrc + kb,         N + 4096 + wave * 4096);
            stage16(Bsrc + kb + 16384, N + 4096 + wave * 4096 + 1024);
            stage16(Bsrc + kb + 32768, N + 4096 + wave * 4096 + 2048);
            stage16(Bsrc + kb + 49152, N + 4096 + wave * 4096 + 3072);
            asm volatile("" ::: "memory");
        }

        #pragma unroll
        for (int rf = 0; rf < 4; ++rf)
            #pragma unroll
            for (int t = 0; t < 4; ++t)
                acc[rf][t] = __builtin_amdgcn_mfma_f32_16x16x32_bf16(
                    a[rf], bfr[t], acc[rf][t], 0, 0, 0);
        cur ^= 1;
    }

    // epilogue. C layout: col = li, row = quad*4 + reg.
    const int mat = nbase >> 9;        // 0=Q 1=K 2=V (uniform per wave)
    const int nn0 = nbase & 511;
    const int bb  = m0 >> 10;          // 64-row block never straddles b
    const int sb  = m0 & 1023;
    if (mat == 2) {
        #pragma unroll
        for (int t = 0; t < 4; ++t) {
            int nn = nn0 + t * 16 + li;
            int h = nn >> 5, d = nn & 31;
            size_t base = ((size_t)(bb * Hh + h) * Dd + d) * 512
                        + (sb >> 5) * 16 + quad * 4;
            #pragma unroll
            for (int p = 0; p < 2; ++p) {      // rf pair (2p, 2p+1)
                u32x4 pk;
                #pragma unroll
                for (int r = 0; r < 4; ++r)
                    pk[r] = pack_bf16(acc[2*p][t][r], acc[2*p+1][t][r]);
                *reinterpret_cast<u32x4*>(Vt32 + base + (size_t)p * 16) = pk;
            }
        }
    } else {
        __hip_bfloat16* dst = (mat == 0) ? Qs : Kh;
        const float sc = (mat == 0) ? QSCALE : 1.0f;
        #pragma unroll
        for (int rf = 0; rf < 4; ++rf) {
            const int srw = sb + rf * 16 + quad * 4;
            #pragma unroll
            for (int t = 0; t < 4; ++t) {
                int nn = nn0 + t * 16 + li;
                int h = nn >> 5, d = nn & 31;
                size_t base = ((size_t)(bb * Hh + h) * Ss + srw) * Dd + d;
                #pragma unroll
                for (int r = 0; r < 4; r += 2) {
                    unsigned w = pack_bf16(acc[rf][t][r]     * sc,
                                           acc[rf][t][r + 1] * sc);
                    dst[base + (size_t)r * Dd] =
                        __builtin_bit_cast(__hip_bfloat16, (unsigned short)(w & 0xffffu));
                    dst[base + (size_t)(r + 1) * Dd] =
                        __builtin_bit_cast(__hip_bfloat16, (unsigned short)(w >> 16));
                }
            }
        }
    }
}

// ---------------- attention (R14 + deferred-PV phase order) ----------------
// grid 1024; (b,h) = blockIdx&127 (XCD-local), ib = blockIdx>>7.
// Wave owns TWO 16-row Q strips (32 rows); j-loop steps 64.
// Iter: Er(4) -> vmcnt(4) -> s_barrier -> ds_read buf[cur] ->
// stage buf[cur^1] -> QK_A -> sm_A -> QK_B -> sm_B -> PV_A+PV_B burst.
__global__ __launch_bounds__(256) void attn_kernel(
    const __hip_bfloat16* __restrict__ Qs,
    const __hip_bfloat16* __restrict__ Kh,
    const __hip_bfloat16* __restrict__ Vt,   // bf16 view of Vti (same bytes)
    const __hip_bfloat16* __restrict__ Er,   // [2048][32] bf16 (row 2047 pad)
    float* __restrict__ out)                 // [B][S][E] f32
{
    const int tid  = threadIdx.x;
    const int wave = tid >> 6;
    const int lane = tid & 63;
    const int li   = lane & 15;
    const int quad = lane >> 4;

    const int c  = blockIdx.x & 127;
    const int b  = c >> 4;
    const int h  = c & 15;
    const int ib = blockIdx.x >> 7;          // 0..7
    const int i0 = ib * 128 + wave * 32;     // strip A rows i0.., B rows i0+16..

    const __hip_bfloat16* Qp  = Qs + (size_t)(b * Hh + h) * Ss * Dd;
    const __hip_bfloat16* Kp  = Kh + (size_t)(b * Hh + h) * Ss * Dd;
    const unsigned*       Vp32 = reinterpret_cast<const unsigned*>(Vt)
                               + (size_t)(b * Hh + h) * Dd * 512;

    __shared__ unsigned pb_lds[4][4][16 * 20];           // 20480 B
    __shared__ __align__(16) unsigned char kvbuf[2][8192];  // K @0, V @4096
    unsigned* pbA0 = pb_lds[wave][0];   // strip A cols 0-31
    unsigned* pbA1 = pb_lds[wave][1];   // strip A cols 32-63
    unsigned* pbB0 = pb_lds[wave][2];   // strip B cols 0-31
    unsigned* pbB1 = pb_lds[wave][3];   // strip B cols 32-63

    // staging addresses (R13 verbatim).
    const int krow  = wave * 16 + (lane >> 2);
    const int kcol8 = ((lane & 3) ^ ((lane >> 3) & 3)) * 8;  // bf16 elems
    const int vrow = wave * 8 + (lane >> 3);
    const int vcol4 = 4 * ((lane & 7) ^ ((lane >> 3) & 7));  // u32 within row
    const int swz = (li & 7) << 4;       // V read-side XOR
    const int kr  = (quad ^ ((li >> 1) & 3)) << 4;  // K read-side chunk

    // prologue: stage j=0 into buf 0.
    stage16(Kp + (size_t)krow * Dd + kcol8, (char*)kvbuf[0] + wave * 1024);
    stage16(Vp32 + (size_t)vrow * 512 + vcol4,
            (char*)kvbuf[0] + 4096 + wave * 1024);
    asm volatile("" ::: "memory");

    const bf16x8 qfA = ldg_frag(Qp + (i0      + li) * Dd + quad * 8);
    const bf16x8 qfB = ldg_frag(Qp + (i0 + 16 + li) * Dd + quad * 8);

    // loop-invariant: bpermute byte-addresses and SOURCE-side band-half
    // selector (see R7 comments). 1 bpermute per band value.
    int addr4[4];
    bool sel[4];
    #pragma unroll
    for (int r = 0; r < 4; ++r) {
        const int row = quad * 4 + r;
        addr4[r] = (16 * quad + ((li - row + 15) & 15)) * 4;
        sel[r]   = (li + row >= 15);       // this lane is a lower-block src
    }
    const int pbw = quad * 80 + li;        // pb write base (u32)
    const int pbr = li * 20 + quad * 4;    // pb read base (16B aligned)

    f32x4 oA0 = f32x4{0,0,0,0}, oA1 = f32x4{0,0,0,0};
    f32x4 oB0 = f32x4{0,0,0,0}, oB1 = f32x4{0,0,0,0};
    f32x4 lsA = f32x4{0,0,0,0}, lsB = f32x4{0,0,0,0};
    const f32x4 zero = f32x4{0,0,0,0};

    bf16x8 ones;
    #pragma unroll
    for (int i = 0; i < 8; ++i) ones[i] = (short)0x3F80;   // bf16 1.0

    // Er rotation peel: window slides by 64 each iter; em'=e3, e0'=e4.
    const int rb0 = 1008 - i0;               // >= 16 for all i0
    bf16x8 em = ldg_frag(Er + (rb0 - 16 + li) * Dd + quad * 8);
    bf16x8 e0 = ldg_frag(Er + (rb0      + li) * Dd + quad * 8);

    int cur = 0;
    for (int j0 = 0; j0 < Ss; j0 += 64) {
        // ---- Er loads (stay in flight across the vmcnt below) ----
        const int rb = j0 - i0 + 1008;
        bf16x8 e1 = ldg_frag(Er + (rb + 16 + li) * Dd + quad * 8);
        bf16x8 e2 = ldg_frag(Er + (rb + 32 + li) * Dd + quad * 8);
        bf16x8 e3 = ldg_frag(Er + (rb + 48 + li) * Dd + quad * 8);
        bf16x8 e4 = ldg_frag(Er + (rb + 64 + li) * Dd + quad * 8);

        // drain my 2 staging ops for buf[cur] (issued last iter), keep the
        // 4 Er loads in flight; barrier makes it block-wide.
        __builtin_amdgcn_sched_barrier(0);
        asm volatile("s_waitcnt vmcnt(4)" ::: "memory");
        __builtin_amdgcn_s_barrier();
        asm volatile("" ::: "memory");
        __builtin_amdgcn_sched_barrier(0);

        // ---- K/V fragments from LDS buf[cur] ----
        const char* Kb = (const char*)kvbuf[cur];
        const char* Vb = Kb + 4096;
        bf16x8 k0 = *reinterpret_cast<const bf16x8*>(Kb + (     li) * 64 + kr);
        bf16x8 k1 = *reinterpret_cast<const bf16x8*>(Kb + (16 + li) * 64 + kr);
        bf16x8 k2 = *reinterpret_cast<const bf16x8*>(Kb + (32 + li) * 64 + kr);
        bf16x8 k3 = *reinterpret_cast<const bf16x8*>(Kb + (48 + li) * 64 + kr);
        bf16x8 v0 = *reinterpret_cast<const bf16x8*>(Vb + (     li) * 128 + ((     quad * 16) ^ swz));
        bf16x8 v1 = *reinterpret_cast<const bf16x8*>(Vb + (16 + li) * 128 + ((     quad * 16) ^ swz));
        bf16x8 v2 = *reinterpret_cast<const bf16x8*>(Vb + (     li) * 128 + ((64 + quad * 16) ^ swz));
        bf16x8 v3 = *reinterpret_cast<const bf16x8*>(Vb + (16 + li) * 128 + ((64 + quad * 16) ^ swz));

        // ---- stage next j-tile into buf[cur^1] (lands under compute) ----
        {
            const int jn = (j0 + 64) & 1023;     // wrap: restage j=0, unused
            char* N = (char*)kvbuf[cur ^ 1];
            stage16(Kp + (size_t)(jn + krow) * Dd + kcol8, N + wave * 1024);
            stage16(Vp32 + (size_t)vrow * 512 + (jn >> 1) + vcol4,
                    N + 4096 + wave * 1024);
            asm volatile("" ::: "memory");
        }

        // ================= strip A QK + softmax -> pbA ==============
        {
            __builtin_amdgcn_s_setprio(1);
            f32x4 s0 = __builtin_amdgcn_mfma_f32_16x16x32_bf16(qfA, k0, zero, 0, 0, 0);
            f32x4 s1 = __builtin_amdgcn_mfma_f32_16x16x32_bf16(qfA, k1, zero, 0, 0, 0);
            f32x4 s2 = __builtin_amdgcn_mfma_f32_16x16x32_bf16(qfA, k2, zero, 0, 0, 0);
            f32x4 s3 = __builtin_amdgcn_mfma_f32_16x16x32_bf16(qfA, k3, zero, 0, 0, 0);
            f32x4 q0 = __builtin_amdgcn_mfma_f32_16x16x32_bf16(qfA, e0, zero, 0, 0, 0);
            f32x4 q1 = __builtin_amdgcn_mfma_f32_16x16x32_bf16(qfA, e1, zero, 0, 0, 0);
            f32x4 q2 = __builtin_amdgcn_mfma_f32_16x16x32_bf16(qfA, e2, zero, 0, 0, 0);
            f32x4 q3 = __builtin_amdgcn_mfma_f32_16x16x32_bf16(qfA, e3, zero, 0, 0, 0);
            f32x4 q4 = __builtin_amdgcn_mfma_f32_16x16x32_bf16(qfA, e4, zero, 0, 0, 0);
            __builtin_amdgcn_s_setprio(0);
            float p0[4], p1[4], p2[4], p3[4];
            #pragma unroll
            for (int r = 0; r < 4; ++r) {
                float m0 = sel[r] ? q0[r] : q1[r];
                float m1 = sel[r] ? q1[r] : q2[r];
                float m2 = sel[r] ? q2[r] : q3[r];
                float m3 = sel[r] ? q3[r] : q4[r];
                p0[r] = EXP2F(s0[r] + bperm_f(addr4[r], m0));
                p1[r] = EXP2F(s1[r] + bperm_f(addr4[r], m1));
                p2[r] = EXP2F(s2[r] + bperm_f(addr4[r], m2));
                p3[r] = EXP2F(s3[r] + bperm_f(addr4[r], m3));
            }
            #pragma unroll
            for (int r = 0; r < 4; ++r) {
                pbA0[pbw + 20 * r] = pack_bf16(p0[r], p1[r]);
                pbA1[pbw + 20 * r] = pack_bf16(p2[r], p3[r]);
            }
        }

        // ================= strip B QK + softmax -> pbB ==============
        // strip B's band block n == strip A's block n-1: uses em,e0..e3.
        {
            __builtin_amdgcn_s_setprio(1);
            f32x4 s0 = __builtin_amdgcn_mfma_f32_16x16x32_bf16(qfB, k0, zero, 0, 0, 0);
            f32x4 s1 = __builtin_amdgcn_mfma_f32_16x16x32_bf16(qfB, k1, zero, 0, 0, 0);
            f32x4 s2 = __builtin_amdgcn_mfma_f32_16x16x32_bf16(qfB, k2, zero, 0, 0, 0);
            f32x4 s3 = __builtin_amdgcn_mfma_f32_16x16x32_bf16(qfB, k3, zero, 0, 0, 0);
            f32x4 q0 = __builtin_amdgcn_mfma_f32_16x16x32_bf16(qfB, em, zero, 0, 0, 0);
            f32x4 q1 = __builtin_amdgcn_mfma_f32_16x16x32_bf16(qfB, e0, zero, 0, 0, 0);
            f32x4 q2 = __builtin_amdgcn_mfma_f32_16x16x32_bf16(qfB, e1, zero, 0, 0, 0);
            f32x4 q3 = __builtin_amdgcn_mfma_f32_16x16x32_bf16(qfB, e2, zero, 0, 0, 0);
            f32x4 q4 = __builtin_amdgcn_mfma_f32_16x16x32_bf16(qfB, e3, zero, 0, 0, 0);
            __builtin_amdgcn_s_setprio(0);
            float p0[4], p1[4], p2[4], p3[4];
            #pragma unroll
            for (int r = 0; r < 4; ++r) {
                float m0 = sel[r] ? q0[r] : q1[r];
                float m1 = sel[r] ? q1[r] : q2[r];
                float m2 = sel[r] ? q2[r] : q3[r];
                float m3 = sel[r] ? q3[r] : q4[r];
                p0[r] = EXP2F(s0[r] + bperm_f(addr4[r], m0));
                p1[r] = EXP2F(s1[r] + bperm_f(addr4[r], m1));
                p2[r] = EXP2F(s2[r] + bperm_f(addr4[r], m2));
                p3[r] = EXP2F(s3[r] + bperm_f(addr4[r], m3));
            }
            #pragma unroll
            for (int r = 0; r < 4; ++r) {
                pbB0[pbw + 20 * r] = pack_bf16(p0[r], p1[r]);
                pbB1[pbw + 20 * r] = pack_bf16(p2[r], p3[r]);
            }
        }

        // ================= PV burst (pbA aged a full strip) =========
        {
            bf16x8 pfA0 = *reinterpret_cast<const bf16x8*>(&pbA0[pbr]);
            bf16x8 pfA1 = *reinterpret_cast<const bf16x8*>(&pbA1[pbr]);
            bf16x8 pfB0 = *reinterpret_cast<const bf16x8*>(&pbB0[pbr]);
            bf16x8 pfB1 = *reinterpret_cast<const bf16x8*>(&pbB1[pbr]);
            __builtin_amdgcn_s_setprio(1);
            oA0 = __builtin_amdgcn_mfma_f32_16x16x32_bf16(pfA0, v0, oA0, 0, 0, 0);
            oA1 = __builtin_amdgcn_mfma_f32_16x16x32_bf16(pfA0, v1, oA1, 0, 0, 0);
            oA0 = __builtin_amdgcn_mfma_f32_16x16x32_bf16(pfA1, v2, oA0, 0, 0, 0);
            oA1 = __builtin_amdgcn_mfma_f32_16x16x32_bf16(pfA1, v3, oA1, 0, 0, 0);
            lsA = __builtin_amdgcn_mfma_f32_16x16x32_bf16(pfA0, ones, lsA, 0, 0, 0);
            lsA = __builtin_amdgcn_mfma_f32_16x16x32_bf16(pfA1, ones, lsA, 0, 0, 0);
            oB0 = __builtin_amdgcn_mfma_f32_16x16x32_bf16(pfB0, v0, oB0, 0, 0, 0);
            oB1 = __builtin_amdgcn_mfma_f32_16x16x32_bf16(pfB0, v1, oB1, 0, 0, 0);
            oB0 = __builtin_amdgcn_mfma_f32_16x16x32_bf16(pfB1, v2, oB0, 0, 0, 0);
            oB1 = __builtin_amdgcn_mfma_f32_16x16x32_bf16(pfB1, v3, oB1, 0, 0, 0);
            lsB = __builtin_amdgcn_mfma_f32_16x16x32_bf16(pfB0, ones, lsB, 0, 0, 0);
            lsB = __builtin_amdgcn_mfma_f32_16x16x32_bf16(pfB1, ones, lsB, 0, 0, 0);
            __builtin_amdgcn_s_setprio(0);
        }

        // rotate Er window; flip buffers.
        em = e3;
        e0 = e4;
        cur ^= 1;
    }

    // ones-MFMA accumulated exact row sums in the same C layout as oA/oB.
    #pragma unroll
    for (int r = 0; r < 4; ++r) {
        lsA[r] = 1.0f / lsA[r];
        lsB[r] = 1.0f / lsB[r];
    }
    #pragma unroll
    for (int r = 0; r < 4; ++r) {
        const int srowA = i0 + quad * 4 + r;
        float* opA = out + ((size_t)b * Ss + srowA) * Ee + h * Dd;
        opA[li]      = oA0[r] * lsA[r];
        opA[16 + li] = oA1[r] * lsA[r];
        float* opB = opA + 16 * Ee;          // srowA + 16
        opB[li]      = oB0[r] * lsB[r];
        opB[16 + li] = oB1[r] * lsB[r];
    }
}

extern "C" void kernel_launch(void* const* d_in, const int* in_sizes, int n_in,
                              void* d_out, int out_size, void* d_ws, size_t ws_size,
                              hipStream_t stream) {
    const float* x  = (const float*)d_in[0];
    const float* Wq = (const float*)d_in[1];
    const float* Wk = (const float*)d_in[2];
    const float* Wv = (const float*)d_in[3];
    const float* Er = (const float*)d_in[4];
    float* out = (float*)d_out;

    // ws layout (bf16 elements; all offsets 16B-aligned)
    __hip_bfloat16* xb  = reinterpret_cast<__hip_bfloat16*>(d_ws);
    __hip_bfloat16* wbb = xb  + (size_t)8192 * 512;
    __hip_bfloat16* erb = wbb + (size_t)1536 * 512;
    __hip_bfloat16* Qs  = erb + 65536;                  // row 2047 = pad
    __hip_bfloat16* Kh  = Qs  + (size_t)Bb * Hh * Ss * Dd;
    __hip_bfloat16* Vt  = Kh  + (size_t)Bb * Hh * Ss * Dd;

    convert_kernel<<<4929, 256, 0, stream>>>(x, Wq, Wk, Wv, Er, xb, wbb, erb);
    proj_kernel<<<dim3(6, 128), 256, 0, stream>>>(
        xb, wbb, Qs, Kh, reinterpret_cast<unsigned*>(Vt));
    attn_kernel<<<dim3(1024), 256, 0, stream>>>(Qs, Kh, Vt, erb, out);
}